// Round 1
// baseline (603.214 us; speedup 1.0000x reference)
//
#include <hip/hip_runtime.h>
#include <hip/hip_bf16.h>

#define DEVFN __device__ __forceinline__

typedef __attribute__((ext_vector_type(4))) float f32x4;
typedef __attribute__((ext_vector_type(8))) short s16x8;
typedef __attribute__((ext_vector_type(8))) __bf16 bf16x8;

union FragU { s16x8 s; bf16x8 b; };

DEVFN short f2bs(float x) {
  union { __hip_bfloat16 h; short s; } u;
  u.h = __float2bfloat16(x);
  return u.s;
}

// in:  [Z][C][L] f32   ->  out: [Z][L][C] bf16 (as short)
__global__ __launch_bounds__(256) void transpose_cvt(
    const float* __restrict__ in, short* __restrict__ out, int C, int L) {
  __shared__ float tile[32][33];
  const int l0 = blockIdx.x * 32, c0 = blockIdx.y * 32;
  const size_t base = (size_t)blockIdx.z * C * L;
  const int tx = threadIdx.x, ty = threadIdx.y;
#pragma unroll
  for (int i = ty; i < 32; i += 8)
    tile[i][tx] = in[base + (size_t)(c0 + i) * L + l0 + tx];
  __syncthreads();
#pragma unroll
  for (int i = ty; i < 32; i += 8)
    out[base + (size_t)(l0 + i) * C + c0 + tx] = f2bs(tile[tx][i]);
}

// C[m][n] = sum_k A[m][k] * Bt[n][k] (+ bias), tiled 128x128, BK=64,
// 4 waves (2x2), each wave 64x64 via 4x4 fragments of 16x16x32 bf16 MFMA.
// OUTMODE: 0 = bf16 store, 1 = f32 store, 2 = sigmoid(scale*acc) f32 store
// BIASMODE: 0 none, 1 per-n (bias[col]), 2 per-m (bias[row])
// AF32: A operand is f32; converted to bf16 while staging into LDS
template <int OUTMODE, int BIASMODE, int AF32>
__global__ __launch_bounds__(256) void gemm_bt(
    const void* __restrict__ Aptr, const short* __restrict__ Btp,
    const float* __restrict__ bias, void* __restrict__ Cptr,
    int K, int lda, int ldb, int ldc,
    long long sA, long long sB, long long sC, float scale) {
  __shared__ short lsA[128 * 64];
  __shared__ short lsB[128 * 64];
  const int tid = threadIdx.x;
  const int lane = tid & 63, wid = tid >> 6;
  const int zb = blockIdx.z;
  const int m0 = blockIdx.y * 128, n0 = blockIdx.x * 128;
  const short* Ab = AF32 ? nullptr : (const short*)Aptr + (size_t)zb * sA;
  const float* Af = AF32 ? (const float*)Aptr + (size_t)zb * sA : nullptr;
  const short* Bt = Btp + (size_t)zb * sB;

  f32x4 acc[4][4] = {};

  const int woffM = (wid >> 1) * 64, woffN = (wid & 1) * 64;
  const int frow = lane & 15, fkg = lane >> 4;

  for (int k0 = 0; k0 < K; k0 += 64) {
    if (k0) __syncthreads();
    if constexpr (!AF32) {
#pragma unroll
      for (int i = 0; i < 4; ++i) {
        int f = tid + i * 256;
        int row = f >> 3, c8 = f & 7;
        *(s16x8*)&lsA[row * 64 + c8 * 8] =
            *(const s16x8*)&Ab[(size_t)(m0 + row) * lda + k0 + c8 * 8];
      }
    } else {
#pragma unroll
      for (int i = 0; i < 8; ++i) {
        int f = tid + i * 256;
        int row = f >> 4, c4 = f & 15;
        f32x4 v = *(const f32x4*)&Af[(size_t)(m0 + row) * lda + k0 + c4 * 4];
        union { short s[4]; unsigned long long q; } cv;
#pragma unroll
        for (int j = 0; j < 4; ++j) cv.s[j] = f2bs(v[j]);
        *(unsigned long long*)&lsA[row * 64 + c4 * 4] = cv.q;
      }
    }
#pragma unroll
    for (int i = 0; i < 4; ++i) {
      int f = tid + i * 256;
      int row = f >> 3, c8 = f & 7;
      *(s16x8*)&lsB[row * 64 + c8 * 8] =
          *(const s16x8*)&Bt[(size_t)(n0 + row) * ldb + k0 + c8 * 8];
    }
    __syncthreads();
#pragma unroll
    for (int kk = 0; kk < 2; ++kk) {
      const int kb = kk * 32 + fkg * 8;
      FragU fa[4], fb[4];
#pragma unroll
      for (int mf = 0; mf < 4; ++mf)
        fa[mf].s = *(const s16x8*)&lsA[(woffM + mf * 16 + frow) * 64 + kb];
#pragma unroll
      for (int nf = 0; nf < 4; ++nf)
        fb[nf].s = *(const s16x8*)&lsB[(woffN + nf * 16 + frow) * 64 + kb];
#pragma unroll
      for (int mf = 0; mf < 4; ++mf)
#pragma unroll
        for (int nf = 0; nf < 4; ++nf)
          acc[mf][nf] = __builtin_amdgcn_mfma_f32_16x16x32_bf16(
              fa[mf].b, fb[nf].b, acc[mf][nf], 0, 0, 0);
    }
  }

  const int rbase = (lane >> 4) * 4, cbase = lane & 15;
#pragma unroll
  for (int mf = 0; mf < 4; ++mf) {
#pragma unroll
    for (int nf = 0; nf < 4; ++nf) {
      const int gcol = n0 + woffN + nf * 16 + cbase;
      float bn = (BIASMODE == 1) ? bias[gcol] : 0.f;
#pragma unroll
      for (int r = 0; r < 4; ++r) {
        const int grow = m0 + woffM + mf * 16 + rbase + r;
        float v = acc[mf][nf][r];
        if constexpr (BIASMODE == 2) v += bias[grow]; else v += bn;
        if constexpr (OUTMODE == 0) {
          ((short*)Cptr)[(size_t)zb * sC + (size_t)grow * ldc + gcol] = f2bs(v);
        } else if constexpr (OUTMODE == 1) {
          ((float*)Cptr)[(size_t)zb * sC + (size_t)grow * ldc + gcol] = v;
        } else {
          float p = 1.0f / (1.0f + __expf(-v * scale));
          ((float*)Cptr)[(size_t)zb * sC + (size_t)grow * ldc + gcol] = p;
        }
      }
    }
  }
}

extern "C" void kernel_launch(void* const* d_in, const int* in_sizes, int n_in,
                              void* d_out, int out_size, void* d_ws, size_t ws_size,
                              hipStream_t stream) {
  const float* in1 = (const float*)d_in[0];   // [16][512][2048]
  const float* in2 = (const float*)d_in[1];   // [16][768][1024]
  const float* Wq1 = (const float*)d_in[2];  const float* bq1 = (const float*)d_in[3];
  const float* Wk1 = (const float*)d_in[4];  const float* bk1 = (const float*)d_in[5];
  const float* Wv1 = (const float*)d_in[6];  const float* bv1 = (const float*)d_in[7];
  const float* Wq2 = (const float*)d_in[8];  const float* bq2 = (const float*)d_in[9];
  const float* Wk2 = (const float*)d_in[10]; const float* bk2 = (const float*)d_in[11];
  const float* Wv2 = (const float*)d_in[12]; const float* bv2 = (const float*)d_in[13];

  float* out = (float*)d_out;
  float* ctx2   = out;                                      // [16][2048][512]
  float* probs2 = out + (size_t)16 * 2048 * 512;            // [16][2048][1024]
  float* ctx1   = probs2 + (size_t)16 * 2048 * 1024;        // [16][1024][512]
  float* probs1 = ctx1 + (size_t)16 * 1024 * 512;           // [16][1024][2048]

  char* ws = (char*)d_ws;
  constexpr size_t O_WQ1T = 0;
  constexpr size_t O_WK1T = O_WQ1T + (size_t)512 * 512 * 2;
  constexpr size_t O_WV1T = O_WK1T + (size_t)512 * 512 * 2;
  constexpr size_t O_WQ2T = O_WV1T + (size_t)512 * 512 * 2;
  constexpr size_t O_WK2T = O_WQ2T + (size_t)768 * 512 * 2;
  constexpr size_t O_WV2T = O_WK2T + (size_t)768 * 512 * 2;
  constexpr size_t O_Q1   = O_WV2T + (size_t)768 * 512 * 2;
  constexpr size_t O_K1   = O_Q1  + (size_t)16 * 2048 * 512 * 2;
  constexpr size_t O_V1T  = O_K1  + (size_t)16 * 2048 * 512 * 2;
  constexpr size_t O_Q2   = O_V1T + (size_t)16 * 2048 * 512 * 2;
  constexpr size_t O_K2   = O_Q2  + (size_t)16 * 1024 * 512 * 2;
  constexpr size_t O_V2T  = O_K2  + (size_t)16 * 1024 * 512 * 2;
  constexpr size_t O_X1B  = O_V2T + (size_t)16 * 1024 * 512 * 2;
  constexpr size_t O_X2B  = O_X1B + (size_t)16 * 2048 * 512 * 2;
  constexpr size_t NEED_FULL = O_X2B + (size_t)16 * 1024 * 768 * 2;

  short* wq1t = (short*)(ws + O_WQ1T);
  short* wk1t = (short*)(ws + O_WK1T);
  short* wv1t = (short*)(ws + O_WV1T);
  short* wq2t = (short*)(ws + O_WQ2T);
  short* wk2t = (short*)(ws + O_WK2T);
  short* wv2t = (short*)(ws + O_WV2T);
  short* q1   = (short*)(ws + O_Q1);
  short* k1   = (short*)(ws + O_K1);
  short* v1t  = (short*)(ws + O_V1T);
  short* q2   = (short*)(ws + O_Q2);
  short* k2   = (short*)(ws + O_K2);
  short* v2t  = (short*)(ws + O_V2T);
  // x1b/x2b: bf16 transposed activations. If ws is too small, stage them in
  // the not-yet-written probs regions of d_out (dead before scores overwrite).
  short* x1b;
  short* x2b;
  if (ws_size >= NEED_FULL) {
    x1b = (short*)(ws + O_X1B);
    x2b = (short*)(ws + O_X2B);
  } else {
    x1b = (short*)probs1;   // 33.5MB <= 134MB region
    x2b = (short*)probs2;   // 25.2MB <= 134MB region
  }

  dim3 blk256(256);
  dim3 blkT(32, 8);

  // ---- stage 0: transpose + bf16 convert ----
  transpose_cvt<<<dim3(64, 16, 16), blkT, 0, stream>>>(in1, x1b, 512, 2048);
  transpose_cvt<<<dim3(32, 24, 16), blkT, 0, stream>>>(in2, x2b, 768, 1024);
  transpose_cvt<<<dim3(16, 16, 1), blkT, 0, stream>>>(Wq1, wq1t, 512, 512);
  transpose_cvt<<<dim3(16, 16, 1), blkT, 0, stream>>>(Wk1, wk1t, 512, 512);
  transpose_cvt<<<dim3(16, 16, 1), blkT, 0, stream>>>(Wv1, wv1t, 512, 512);
  transpose_cvt<<<dim3(16, 24, 1), blkT, 0, stream>>>(Wq2, wq2t, 768, 512);
  transpose_cvt<<<dim3(16, 24, 1), blkT, 0, stream>>>(Wk2, wk2t, 768, 512);
  transpose_cvt<<<dim3(16, 24, 1), blkT, 0, stream>>>(Wv2, wv2t, 768, 512);

  // ---- stage 1: projections (bf16 out) ----
  // q1/k1: [32768][512] = x1b @ w*t^T, bias per-n
  gemm_bt<0, 1, 0><<<dim3(4, 256, 1), blk256, 0, stream>>>(
      x1b, wq1t, bq1, q1, 512, 512, 512, 512, 0, 0, 0, 1.f);
  gemm_bt<0, 1, 0><<<dim3(4, 256, 1), blk256, 0, stream>>>(
      x1b, wk1t, bk1, k1, 512, 512, 512, 512, 0, 0, 0, 1.f);
  // v1t[b]: [512][2048] = wv1t @ x1b[b]^T, bias per-m
  gemm_bt<0, 2, 0><<<dim3(16, 4, 16), blk256, 0, stream>>>(
      wv1t, x1b, bv1, v1t, 512, 512, 512, 2048,
      0, (long long)2048 * 512, (long long)512 * 2048, 1.f);
  // q2/k2: [16384][512] = x2b @ w*t^T
  gemm_bt<0, 1, 0><<<dim3(4, 128, 1), blk256, 0, stream>>>(
      x2b, wq2t, bq2, q2, 768, 768, 768, 512, 0, 0, 0, 1.f);
  gemm_bt<0, 1, 0><<<dim3(4, 128, 1), blk256, 0, stream>>>(
      x2b, wk2t, bk2, k2, 768, 768, 768, 512, 0, 0, 0, 1.f);
  // v2t[b]: [512][1024] = wv2t @ x2b[b]^T
  gemm_bt<0, 2, 0><<<dim3(8, 4, 16), blk256, 0, stream>>>(
      wv2t, x2b, bv2, v2t, 768, 768, 768, 1024,
      0, (long long)1024 * 768, (long long)512 * 1024, 1.f);

  const float scale = 0.04419417382415922f;  // 1/sqrt(512)

  // ---- stage 2: scores + sigmoid -> probs (f32, straight to d_out) ----
  // probs1[b] [1024][2048] = sigmoid(scale * q2[b] @ k1[b]^T)
  gemm_bt<2, 0, 0><<<dim3(16, 8, 16), blk256, 0, stream>>>(
      q2, k1, nullptr, probs1, 512, 512, 512, 2048,
      (long long)1024 * 512, (long long)2048 * 512, (long long)1024 * 2048, scale);
  // probs2[b] [2048][1024] = sigmoid(scale * q1[b] @ k2[b]^T)
  gemm_bt<2, 0, 0><<<dim3(8, 16, 16), blk256, 0, stream>>>(
      q1, k2, nullptr, probs2, 512, 512, 512, 1024,
      (long long)2048 * 512, (long long)1024 * 512, (long long)2048 * 1024, scale);

  // ---- stage 3: ctx = probs @ v (A is f32 probs, staged->bf16) ----
  // ctx1[b] [1024][512] = probs1[b] @ v1t[b]^T
  gemm_bt<1, 0, 1><<<dim3(4, 8, 16), blk256, 0, stream>>>(
      probs1, v1t, nullptr, ctx1, 2048, 2048, 2048, 512,
      (long long)1024 * 2048, (long long)512 * 2048, (long long)1024 * 512, 1.f);
  // ctx2[b] [2048][512] = probs2[b] @ v2t[b]^T
  gemm_bt<1, 0, 1><<<dim3(4, 16, 16), blk256, 0, stream>>>(
      probs2, v2t, nullptr, ctx2, 1024, 1024, 1024, 512,
      (long long)2048 * 1024, (long long)512 * 1024, (long long)2048 * 512, 1.f);
}

// Round 2
// 570.301 us; speedup vs baseline: 1.0577x; 1.0577x over previous
//
#include <hip/hip_runtime.h>
#include <hip/hip_bf16.h>

#define DEVFN __device__ __forceinline__

typedef __attribute__((ext_vector_type(4))) float f32x4;
typedef __attribute__((ext_vector_type(8))) short s16x8;
typedef __attribute__((ext_vector_type(2))) short s16x2;
typedef __attribute__((ext_vector_type(8))) __bf16 bf16x8;

union FragU { s16x8 s; bf16x8 b; };

DEVFN short f2bs(float x) {
  union { __hip_bfloat16 h; short s; } u;
  u.h = __float2bfloat16(x);
  return u.s;
}

DEVFN void gload16(const void* g, void* l) {
  __builtin_amdgcn_global_load_lds(
      (const __attribute__((address_space(1))) void*)g,
      (__attribute__((address_space(3))) void*)l, 16, 0, 0);
}

// in: [Z][C][L] f32 -> out: [Z][L][C] bf16. Block (32,8): C-tile 64, L-tile 32.
__global__ __launch_bounds__(256) void transpose_cvt(
    const float* __restrict__ in, short* __restrict__ out, int C, int L) {
  __shared__ float tile[64][33];
  const int l0 = blockIdx.x * 32, c0 = blockIdx.y * 64;
  const size_t base = (size_t)blockIdx.z * C * L;
  const int tx = threadIdx.x, ty = threadIdx.y;
#pragma unroll
  for (int i = ty; i < 64; i += 8)
    tile[i][tx] = in[base + (size_t)(c0 + i) * L + l0 + tx];
  __syncthreads();
#pragma unroll
  for (int i = ty; i < 32; i += 8) {
    s16x2 v;
    v[0] = f2bs(tile[2 * tx][i]);
    v[1] = f2bs(tile[2 * tx + 1][i]);
    *(s16x2*)&out[base + (size_t)(l0 + i) * C + c0 + 2 * tx] = v;
  }
}

__global__ __launch_bounds__(256) void concat_bias(
    const float* __restrict__ a, const float* __restrict__ b,
    float* __restrict__ o, int n) {
  int i = blockIdx.x * 256 + threadIdx.x;
  if (i < n) o[i] = a[i];
  else if (i < 2 * n) o[i] = b[i - n];
}

// C[m][n] = sum_k A[m][k]*Bt[n][k] (+bias). 128x128 tile, BK=64, 4 waves.
// OUTMODE: 0=bf16 store, 1=f32 store, 2=sigmoid f32 store,
//          3=sigmoid f32 store + bf16 store to C2p
// BIASMODE: 0 none, 1 per-n, 2 per-m.  AF32: A is f32, cvt during staging.
template <int OUTMODE, int BIASMODE, int AF32>
__global__ __launch_bounds__(256) void gemm_bt(
    const void* __restrict__ Aptr, const short* __restrict__ Btp,
    const float* __restrict__ bias, void* __restrict__ Cptr,
    short* __restrict__ C2p,
    int K, int lda, int ldb, int ldc,
    long long sA, long long sB, long long sC, float scale) {
  __shared__ short lsA[128 * 64];
  __shared__ short lsB[128 * 64];
  const int tid = threadIdx.x;
  const int lane = tid & 63, wid = tid >> 6;
  const int zb = blockIdx.z;
  const int m0 = blockIdx.y * 128, n0 = blockIdx.x * 128;
  const short* Ab = AF32 ? nullptr : (const short*)Aptr + (size_t)zb * sA;
  const float* Af = AF32 ? (const float*)Aptr + (size_t)zb * sA : nullptr;
  const short* Bt = Btp + (size_t)zb * sB;

  f32x4 acc[4][4] = {};
  const int woffM = (wid >> 1) * 64, woffN = (wid & 1) * 64;
  const int frow = lane & 15, fkg = lane >> 4;

  for (int k0 = 0; k0 < K; k0 += 64) {
    if (k0) __syncthreads();
    if constexpr (!AF32) {
#pragma unroll
      for (int i = 0; i < 4; ++i) {
        const int f = i * 4096 + tid * 16;
        const int row = f >> 7, colb = f & 127;
        gload16((const char*)Ab + ((size_t)(m0 + row) * lda + k0) * 2 + colb,
                (char*)lsA + f);
      }
    } else {
#pragma unroll
      for (int i = 0; i < 8; ++i) {
        int f = tid + i * 256;
        int row = f >> 4, c4 = f & 15;
        f32x4 v = *(const f32x4*)&Af[(size_t)(m0 + row) * lda + k0 + c4 * 4];
        union { short s[4]; unsigned long long q; } cv;
#pragma unroll
        for (int j = 0; j < 4; ++j) cv.s[j] = f2bs(v[j]);
        *(unsigned long long*)&lsA[row * 64 + c4 * 4] = cv.q;
      }
    }
#pragma unroll
    for (int i = 0; i < 4; ++i) {
      const int f = i * 4096 + tid * 16;
      const int row = f >> 7, colb = f & 127;
      gload16((const char*)Bt + ((size_t)(n0 + row) * ldb + k0) * 2 + colb,
              (char*)lsB + f);
    }
    __syncthreads();
#pragma unroll
    for (int kk = 0; kk < 2; ++kk) {
      const int kb = kk * 32 + fkg * 8;
      FragU fa[4], fb[4];
#pragma unroll
      for (int mf = 0; mf < 4; ++mf)
        fa[mf].s = *(const s16x8*)&lsA[(woffM + mf * 16 + frow) * 64 + kb];
#pragma unroll
      for (int nf = 0; nf < 4; ++nf)
        fb[nf].s = *(const s16x8*)&lsB[(woffN + nf * 16 + frow) * 64 + kb];
#pragma unroll
      for (int mf = 0; mf < 4; ++mf)
#pragma unroll
        for (int nf = 0; nf < 4; ++nf)
          acc[mf][nf] = __builtin_amdgcn_mfma_f32_16x16x32_bf16(
              fa[mf].b, fb[nf].b, acc[mf][nf], 0, 0, 0);
    }
  }

  const int rbase = (lane >> 4) * 4, cbase = lane & 15;
#pragma unroll
  for (int mf = 0; mf < 4; ++mf) {
#pragma unroll
    for (int nf = 0; nf < 4; ++nf) {
      const int gcol = n0 + woffN + nf * 16 + cbase;
      float bn = (BIASMODE == 1) ? bias[gcol] : 0.f;
#pragma unroll
      for (int r = 0; r < 4; ++r) {
        const int grow = m0 + woffM + mf * 16 + rbase + r;
        const size_t idx = (size_t)zb * sC + (size_t)grow * ldc + gcol;
        float v = acc[mf][nf][r];
        if constexpr (BIASMODE == 2) v += bias[grow]; else v += bn;
        if constexpr (OUTMODE == 0) {
          ((short*)Cptr)[idx] = f2bs(v);
        } else if constexpr (OUTMODE == 1) {
          ((float*)Cptr)[idx] = v;
        } else if constexpr (OUTMODE == 2) {
          ((float*)Cptr)[idx] = 1.0f / (1.0f + __expf(-v * scale));
        } else {
          float p = 1.0f / (1.0f + __expf(-v * scale));
          ((float*)Cptr)[idx] = p;
          C2p[idx] = f2bs(p);
        }
      }
    }
  }
}

extern "C" void kernel_launch(void* const* d_in, const int* in_sizes, int n_in,
                              void* d_out, int out_size, void* d_ws, size_t ws_size,
                              hipStream_t stream) {
  const float* in1 = (const float*)d_in[0];   // [16][512][2048]
  const float* in2 = (const float*)d_in[1];   // [16][768][1024]
  const float* Wq1 = (const float*)d_in[2];  const float* bq1 = (const float*)d_in[3];
  const float* Wk1 = (const float*)d_in[4];  const float* bk1 = (const float*)d_in[5];
  const float* Wv1 = (const float*)d_in[6];  const float* bv1 = (const float*)d_in[7];
  const float* Wq2 = (const float*)d_in[8];  const float* bq2 = (const float*)d_in[9];
  const float* Wk2 = (const float*)d_in[10]; const float* bk2 = (const float*)d_in[11];
  const float* Wv2 = (const float*)d_in[12]; const float* bv2 = (const float*)d_in[13];

  float* out = (float*)d_out;
  float* ctx2   = out;                                      // [16][2048][512]
  float* probs2 = out + (size_t)16 * 2048 * 512;            // [16][2048][1024]
  float* ctx1   = probs2 + (size_t)16 * 2048 * 1024;        // [16][1024][512]
  float* probs1 = ctx1 + (size_t)16 * 1024 * 512;           // [16][1024][2048]

  char* ws = (char*)d_ws;
  // weights (wq|wk adjacent for merged projection)
  constexpr size_t O_WQ1T = 0;
  constexpr size_t O_WK1T = O_WQ1T + (size_t)512 * 512 * 2;
  constexpr size_t O_WV1T = O_WK1T + (size_t)512 * 512 * 2;
  constexpr size_t O_WQ2T = O_WV1T + (size_t)512 * 512 * 2;
  constexpr size_t O_WK2T = O_WQ2T + (size_t)768 * 512 * 2;
  constexpr size_t O_WV2T = O_WK2T + (size_t)768 * 512 * 2;
  constexpr size_t O_B1   = O_WV2T + (size_t)768 * 512 * 2;
  constexpr size_t O_B2   = O_B1 + 4096;
  constexpr size_t O_QK1  = O_B2 + 4096;                          // [32768][1024] bf16
  constexpr size_t O_V1T  = O_QK1 + (size_t)32768 * 1024 * 2;     // [16][512][2048]
  constexpr size_t O_QK2  = O_V1T + (size_t)16 * 512 * 2048 * 2;  // [16384][1024]
  constexpr size_t O_V2T  = O_QK2 + (size_t)16384 * 1024 * 2;     // [16][512][1024]
  constexpr size_t O_X1B  = O_V2T + (size_t)16 * 512 * 1024 * 2;  // [32768][512]
  constexpr size_t O_X2B  = O_X1B + (size_t)32768 * 512 * 2;      // [16384][768]
  constexpr size_t O_PB1  = O_X2B + (size_t)16384 * 768 * 2;      // [16][1024][2048] bf16
  constexpr size_t O_PB2  = O_PB1 + (size_t)16 * 1024 * 2048 * 2; // [16][2048][1024] bf16
  constexpr size_t NEED_A = O_PB2 + (size_t)16 * 2048 * 1024 * 2;
  constexpr size_t NEED_B = O_PB1;  // no bf16-probs scratch

  short* wq1t = (short*)(ws + O_WQ1T);
  short* wv1t = (short*)(ws + O_WV1T);
  short* wq2t = (short*)(ws + O_WQ2T);
  short* wk2t = (short*)(ws + O_WK2T);
  short* wv2t = (short*)(ws + O_WV2T);
  short* wk1t = (short*)(ws + O_WK1T);
  float* b1c  = (float*)(ws + O_B1);
  float* b2c  = (float*)(ws + O_B2);
  short* qk1  = (short*)(ws + O_QK1);
  short* v1t  = (short*)(ws + O_V1T);
  short* qk2  = (short*)(ws + O_QK2);
  short* v2t  = (short*)(ws + O_V2T);
  short* x1b  = (short*)(ws + O_X1B);
  short* x2b  = (short*)(ws + O_X2B);
  short* pb1  = (short*)(ws + O_PB1);
  short* pb2  = (short*)(ws + O_PB2);

  const bool tierA = ws_size >= NEED_A;   // bf16 probs scratch fits
  const bool tierB = ws_size >= NEED_B;   // activations fit in ws
  if (!tierB) {                            // stage x in not-yet-written probs
    x1b = (short*)probs1;
    x2b = (short*)probs2;
  }

  dim3 blk256(256);
  dim3 blkT(32, 8);

  // ---- stage 0: transposes + bias concat ----
  transpose_cvt<<<dim3(64, 8, 16), blkT, 0, stream>>>(in1, x1b, 512, 2048);
  transpose_cvt<<<dim3(32, 12, 16), blkT, 0, stream>>>(in2, x2b, 768, 1024);
  transpose_cvt<<<dim3(16, 8, 1), blkT, 0, stream>>>(Wq1, wq1t, 512, 512);
  transpose_cvt<<<dim3(16, 8, 1), blkT, 0, stream>>>(Wk1, wk1t, 512, 512);
  transpose_cvt<<<dim3(16, 8, 1), blkT, 0, stream>>>(Wv1, wv1t, 512, 512);
  transpose_cvt<<<dim3(16, 12, 1), blkT, 0, stream>>>(Wq2, wq2t, 768, 512);
  transpose_cvt<<<dim3(16, 12, 1), blkT, 0, stream>>>(Wk2, wk2t, 768, 512);
  transpose_cvt<<<dim3(16, 12, 1), blkT, 0, stream>>>(Wv2, wv2t, 768, 512);
  concat_bias<<<dim3(4), blk256, 0, stream>>>(bq1, bk1, b1c, 512);
  concat_bias<<<dim3(4), blk256, 0, stream>>>(bq2, bk2, b2c, 512);

  // ---- stage 1: projections ----
  // qk1 [32768][1024] = x1b @ [wq1t|wk1t]^T  (cols 0-511 = q1, 512-1023 = k1)
  gemm_bt<0, 1, 0><<<dim3(8, 256, 1), blk256, 0, stream>>>(
      x1b, wq1t, b1c, qk1, nullptr, 512, 512, 512, 1024, 0, 0, 0, 1.f);
  // qk2 [16384][1024] = x2b @ [wq2t|wk2t]^T
  gemm_bt<0, 1, 0><<<dim3(8, 128, 1), blk256, 0, stream>>>(
      x2b, wq2t, b2c, qk2, nullptr, 768, 768, 768, 1024, 0, 0, 0, 1.f);
  // v1t[b] [512][2048] = wv1t @ x1b[b]^T  (bias per-m)
  gemm_bt<0, 2, 0><<<dim3(16, 4, 16), blk256, 0, stream>>>(
      wv1t, x1b, bv1, v1t, nullptr, 512, 512, 512, 2048,
      0, (long long)2048 * 512, (long long)512 * 2048, 1.f);
  // v2t[b] [512][1024] = wv2t @ x2b[b]^T
  gemm_bt<0, 2, 0><<<dim3(8, 4, 16), blk256, 0, stream>>>(
      wv2t, x2b, bv2, v2t, nullptr, 768, 768, 768, 1024,
      0, (long long)1024 * 768, (long long)512 * 1024, 1.f);

  const float scale = 0.04419417382415922f;  // 1/sqrt(512)
  const short* q1p = qk1;        // lda 1024
  const short* k1p = qk1 + 512;
  const short* q2p = qk2;
  const short* k2p = qk2 + 512;

  if (tierA) {
    // ---- stage 2: probs f32 -> d_out, bf16 -> ws ----
    gemm_bt<3, 0, 0><<<dim3(16, 8, 16), blk256, 0, stream>>>(
        q2p, k1p, nullptr, probs1, pb1, 512, 1024, 1024, 2048,
        (long long)1024 * 1024, (long long)2048 * 1024, (long long)1024 * 2048, scale);
    gemm_bt<3, 0, 0><<<dim3(8, 16, 16), blk256, 0, stream>>>(
        q1p, k2p, nullptr, probs2, pb2, 512, 1024, 1024, 1024,
        (long long)2048 * 1024, (long long)1024 * 1024, (long long)2048 * 1024, scale);
    // ---- stage 3: ctx = probs(bf16) @ v^T ----
    gemm_bt<1, 0, 0><<<dim3(4, 8, 16), blk256, 0, stream>>>(
        pb1, v1t, nullptr, ctx1, nullptr, 2048, 2048, 2048, 512,
        (long long)1024 * 2048, (long long)512 * 2048, (long long)1024 * 512, 1.f);
    gemm_bt<1, 0, 0><<<dim3(4, 16, 16), blk256, 0, stream>>>(
        pb2, v2t, nullptr, ctx2, nullptr, 1024, 1024, 1024, 512,
        (long long)2048 * 1024, (long long)512 * 1024, (long long)2048 * 512, 1.f);
  } else {
    // fallback: f32 probs only, ctx re-reads f32 probs (AF32 staging)
    gemm_bt<2, 0, 0><<<dim3(16, 8, 16), blk256, 0, stream>>>(
        q2p, k1p, nullptr, probs1, nullptr, 512, 1024, 1024, 2048,
        (long long)1024 * 1024, (long long)2048 * 1024, (long long)1024 * 2048, scale);
    gemm_bt<2, 0, 0><<<dim3(8, 16, 16), blk256, 0, stream>>>(
        q1p, k2p, nullptr, probs2, nullptr, 512, 1024, 1024, 1024,
        (long long)2048 * 1024, (long long)1024 * 1024, (long long)2048 * 1024, scale);
    gemm_bt<1, 0, 1><<<dim3(4, 8, 16), blk256, 0, stream>>>(
        probs1, v1t, nullptr, ctx1, nullptr, 2048, 2048, 2048, 512,
        (long long)1024 * 2048, (long long)512 * 2048, (long long)1024 * 512, 1.f);
    gemm_bt<1, 0, 1><<<dim3(4, 16, 16), blk256, 0, stream>>>(
        probs2, v2t, nullptr, ctx2, nullptr, 1024, 1024, 1024, 512,
        (long long)2048 * 1024, (long long)512 * 1024, (long long)2048 * 512, 1.f);
  }
}

// Round 3
// 541.089 us; speedup vs baseline: 1.1148x; 1.0540x over previous
//
#include <hip/hip_runtime.h>
#include <hip/hip_bf16.h>

#define DEVFN __device__ __forceinline__

typedef __attribute__((ext_vector_type(4))) float f32x4;
typedef __attribute__((ext_vector_type(8))) short s16x8;
typedef __attribute__((ext_vector_type(2))) short s16x2;
typedef __attribute__((ext_vector_type(8))) __bf16 bf16x8;

union FragU { s16x8 s; bf16x8 b; };

DEVFN short f2bs(float x) {
  union { __hip_bfloat16 h; short s; } u;
  u.h = __float2bfloat16(x);
  return u.s;
}

DEVFN void gload16(const void* g, void* l) {
  __builtin_amdgcn_global_load_lds(
      (const __attribute__((address_space(1))) void*)g,
      (__attribute__((address_space(3))) void*)l, 16, 0, 0);
}

// in: [Z][C][L] f32 -> out: [Z][L][C] bf16. Block (32,8): C-tile 64, L-tile 32.
__global__ __launch_bounds__(256) void transpose_cvt(
    const float* __restrict__ in, short* __restrict__ out, int C, int L) {
  __shared__ float tile[64][33];
  const int l0 = blockIdx.x * 32, c0 = blockIdx.y * 64;
  const size_t base = (size_t)blockIdx.z * C * L;
  const int tx = threadIdx.x, ty = threadIdx.y;
#pragma unroll
  for (int i = ty; i < 64; i += 8)
    tile[i][tx] = in[base + (size_t)(c0 + i) * L + l0 + tx];
  __syncthreads();
#pragma unroll
  for (int i = ty; i < 32; i += 8) {
    s16x2 v;
    v[0] = f2bs(tile[2 * tx][i]);
    v[1] = f2bs(tile[2 * tx + 1][i]);
    *(s16x2*)&out[base + (size_t)(l0 + i) * C + c0 + 2 * tx] = v;
  }
}

// All six weight transposes (512x512 / 768x512) + both bias concats, one launch.
__global__ __launch_bounds__(256) void prep_weights(
    const float* __restrict__ Wq1, const float* __restrict__ Wk1,
    const float* __restrict__ Wv1, const float* __restrict__ Wq2,
    const float* __restrict__ Wk2, const float* __restrict__ Wv2,
    short* wq1t, short* wk1t, short* wv1t,
    short* wq2t, short* wk2t, short* wv2t,
    const float* __restrict__ bq1, const float* __restrict__ bk1,
    const float* __restrict__ bq2, const float* __restrict__ bk2,
    float* b1c, float* b2c) {
  const int z = blockIdx.z;
  if (z == 6) {
    if (blockIdx.y != 0 || blockIdx.x >= 8) return;
    const int bx = blockIdx.x;
    const int tid = threadIdx.y * 32 + threadIdx.x;
    const int i = (bx & 3) * 256 + tid;  // 0..1023
    const float* s = (bx < 4) ? ((i < 512) ? bq1 : bk1)
                              : ((i < 512) ? bq2 : bk2);
    float* d = (bx < 4) ? b1c : b2c;
    d[i] = s[i & 511];
    return;
  }
  const float* W; short* O; int C;
  switch (z) {
    case 0: W = Wq1; O = wq1t; C = 512; break;
    case 1: W = Wk1; O = wk1t; C = 512; break;
    case 2: W = Wv1; O = wv1t; C = 512; break;
    case 3: W = Wq2; O = wq2t; C = 768; break;
    case 4: W = Wk2; O = wk2t; C = 768; break;
    default: W = Wv2; O = wv2t; C = 768; break;
  }
  if (blockIdx.y * 64 >= (unsigned)C) return;
  const int L = 512;
  __shared__ float tile[64][33];
  const int l0 = blockIdx.x * 32, c0 = blockIdx.y * 64;
  const int tx = threadIdx.x, ty = threadIdx.y;
#pragma unroll
  for (int i = ty; i < 64; i += 8)
    tile[i][tx] = W[(size_t)(c0 + i) * L + l0 + tx];
  __syncthreads();
#pragma unroll
  for (int i = ty; i < 32; i += 8) {
    s16x2 v;
    v[0] = f2bs(tile[2 * tx][i]);
    v[1] = f2bs(tile[2 * tx + 1][i]);
    *(s16x2*)&O[(size_t)(l0 + i) * C + c0 + 2 * tx] = v;
  }
}

// ---------------------------------------------------------------------------
// Pipelined GEMM: C[m][n] = sum_k A[m][k]*Bt[n][k] (+bias).
// 128x128 tile, BK=32, 3 LDS buffers (48KB), prefetch depth 2, counted
// vmcnt(4) (never 0 in steady state), one barrier per K-step, XOR swizzle
// (col ^= (row&3)<<4) on LDS cols (stage-source pre-swizzled; involution),
// setprio(1) around the MFMA cluster.
// OUTMODE: 0=bf16, 1=f32, 2=sigmoid f32, 3=sigmoid f32 + bf16 to C2p
// BIASMODE: 0 none, 1 per-n, 2 per-m.
// ---------------------------------------------------------------------------
template <int OUTMODE, int BIASMODE>
__global__ __launch_bounds__(256, 3) void gemm_p(
    const short* __restrict__ Ap, const short* __restrict__ Btp,
    const float* __restrict__ bias, void* __restrict__ Cptr,
    short* __restrict__ C2p,
    int K, int lda, int ldb, int ldc,
    long long sA, long long sB, long long sC, float scale) {
  __shared__ __align__(16) short smem[3 * 8192];  // [buf][A 4096 | B 4096]
  const int tid = threadIdx.x;
  const int lane = tid & 63, wid = tid >> 6;
  const int zb = blockIdx.z;
  const int m0 = blockIdx.y * 128, n0 = blockIdx.x * 128;
  const char* Ab = (const char*)(Ap + (size_t)zb * sA);
  const char* Bb = (const char*)(Btp + (size_t)zb * sB);
  const size_t lda2 = (size_t)lda * 2, ldb2 = (size_t)ldb * 2;

  // staging geometry: issue i covers rows i*64 + (tid>>2), col (tid&3)*16.
  const int srow = tid >> 2;                       // 0..63
  const int scol = ((tid & 3) * 16) ^ (((srow & 3)) << 4);  // pre-swizzled src col
  const int sdst = tid * 16;

  f32x4 acc[4][4] = {};
  const int woffM = (wid >> 1) * 64, woffN = (wid & 1) * 64;
  const int frow = lane & 15, fkg = lane >> 4;
  const int colp = (fkg * 16) ^ ((frow & 3) << 4);  // swizzled frag col byte
  const int NT = K >> 5;

#define STAGE(t)                                                               \
  {                                                                            \
    const int buf_ = (t) % 3;                                                  \
    const size_t k0b_ = (size_t)(t) * 64;                                      \
    char* la_ = (char*)&smem[buf_ * 8192];                                     \
    char* lb_ = la_ + 8192;                                                    \
    _Pragma("unroll")                                                          \
    for (int i = 0; i < 2; ++i) {                                              \
      gload16(Ab + (size_t)(m0 + i * 64 + srow) * lda2 + k0b_ + scol,          \
              la_ + i * 4096 + sdst);                                          \
      gload16(Bb + (size_t)(n0 + i * 64 + srow) * ldb2 + k0b_ + scol,          \
              lb_ + i * 4096 + sdst);                                          \
    }                                                                          \
  }

  STAGE(0);
  STAGE(1);
  asm volatile("s_waitcnt vmcnt(4)" ::: "memory");
  __builtin_amdgcn_sched_barrier(0);
  __builtin_amdgcn_s_barrier();

  for (int t = 0; t < NT; ++t) {
    if (t + 2 < NT) STAGE(t + 2);
    const char* la = (const char*)&smem[(t % 3) * 8192];
    const char* lb = la + 8192;
    FragU fa[4], fb[4];
#pragma unroll
    for (int mf = 0; mf < 4; ++mf)
      fa[mf].s = *(const s16x8*)(la + (woffM + mf * 16 + frow) * 64 + colp);
#pragma unroll
    for (int nf = 0; nf < 4; ++nf)
      fb[nf].s = *(const s16x8*)(lb + (woffN + nf * 16 + frow) * 64 + colp);
    __builtin_amdgcn_s_setprio(1);
#pragma unroll
    for (int mf = 0; mf < 4; ++mf)
#pragma unroll
      for (int nf = 0; nf < 4; ++nf)
        acc[mf][nf] = __builtin_amdgcn_mfma_f32_16x16x32_bf16(
            fa[mf].b, fb[nf].b, acc[mf][nf], 0, 0, 0);
    __builtin_amdgcn_s_setprio(0);
    if (t + 2 < NT)
      asm volatile("s_waitcnt vmcnt(4) lgkmcnt(0)" ::: "memory");
    else
      asm volatile("s_waitcnt vmcnt(0) lgkmcnt(0)" ::: "memory");
    __builtin_amdgcn_sched_barrier(0);
    __builtin_amdgcn_s_barrier();
  }
#undef STAGE

  const int rbase = (lane >> 4) * 4, cbase = lane & 15;
#pragma unroll
  for (int mf = 0; mf < 4; ++mf) {
#pragma unroll
    for (int nf = 0; nf < 4; ++nf) {
      const int gcol = n0 + woffN + nf * 16 + cbase;
      float bn = (BIASMODE == 1) ? bias[gcol] : 0.f;
#pragma unroll
      for (int r = 0; r < 4; ++r) {
        const int grow = m0 + woffM + mf * 16 + rbase + r;
        const size_t idx = (size_t)zb * sC + (size_t)grow * ldc + gcol;
        float v = acc[mf][nf][r];
        if constexpr (BIASMODE == 2) v += bias[grow]; else v += bn;
        if constexpr (OUTMODE == 0) {
          ((short*)Cptr)[idx] = f2bs(v);
        } else if constexpr (OUTMODE == 1) {
          ((float*)Cptr)[idx] = v;
        } else if constexpr (OUTMODE == 2) {
          ((float*)Cptr)[idx] = 1.0f / (1.0f + __expf(-v * scale));
        } else {
          float p = 1.0f / (1.0f + __expf(-v * scale));
          ((float*)Cptr)[idx] = p;
          C2p[idx] = f2bs(p);
        }
      }
    }
  }
}

// ---------------------------------------------------------------------------
// Fallback (known-good from R1): reg/gload staged 128x128 BK=64 GEMM.
// ---------------------------------------------------------------------------
template <int OUTMODE, int BIASMODE, int AF32>
__global__ __launch_bounds__(256) void gemm_bt(
    const void* __restrict__ Aptr, const short* __restrict__ Btp,
    const float* __restrict__ bias, void* __restrict__ Cptr,
    short* __restrict__ C2p,
    int K, int lda, int ldb, int ldc,
    long long sA, long long sB, long long sC, float scale) {
  __shared__ __align__(16) short lsA[128 * 64];
  __shared__ __align__(16) short lsB[128 * 64];
  const int tid = threadIdx.x;
  const int lane = tid & 63, wid = tid >> 6;
  const int zb = blockIdx.z;
  const int m0 = blockIdx.y * 128, n0 = blockIdx.x * 128;
  const short* Ab = AF32 ? nullptr : (const short*)Aptr + (size_t)zb * sA;
  const float* Af = AF32 ? (const float*)Aptr + (size_t)zb * sA : nullptr;
  const short* Bt = Btp + (size_t)zb * sB;

  f32x4 acc[4][4] = {};
  const int woffM = (wid >> 1) * 64, woffN = (wid & 1) * 64;
  const int frow = lane & 15, fkg = lane >> 4;

  for (int k0 = 0; k0 < K; k0 += 64) {
    if (k0) __syncthreads();
    if constexpr (!AF32) {
#pragma unroll
      for (int i = 0; i < 4; ++i) {
        const int f = i * 4096 + tid * 16;
        const int row = f >> 7, colb = f & 127;
        gload16((const char*)Ab + ((size_t)(m0 + row) * lda + k0) * 2 + colb,
                (char*)lsA + f);
      }
    } else {
#pragma unroll
      for (int i = 0; i < 8; ++i) {
        int f = tid + i * 256;
        int row = f >> 4, c4 = f & 15;
        f32x4 v = *(const f32x4*)&Af[(size_t)(m0 + row) * lda + k0 + c4 * 4];
        union { short s[4]; unsigned long long q; } cv;
#pragma unroll
        for (int j = 0; j < 4; ++j) cv.s[j] = f2bs(v[j]);
        *(unsigned long long*)&lsA[row * 64 + c4 * 4] = cv.q;
      }
    }
#pragma unroll
    for (int i = 0; i < 4; ++i) {
      const int f = i * 4096 + tid * 16;
      const int row = f >> 7, colb = f & 127;
      gload16((const char*)Bt + ((size_t)(n0 + row) * ldb + k0) * 2 + colb,
              (char*)lsB + f);
    }
    __syncthreads();
#pragma unroll
    for (int kk = 0; kk < 2; ++kk) {
      const int kb = kk * 32 + fkg * 8;
      FragU fa[4], fb[4];
#pragma unroll
      for (int mf = 0; mf < 4; ++mf)
        fa[mf].s = *(const s16x8*)&lsA[(woffM + mf * 16 + frow) * 64 + kb];
#pragma unroll
      for (int nf = 0; nf < 4; ++nf)
        fb[nf].s = *(const s16x8*)&lsB[(woffN + nf * 16 + frow) * 64 + kb];
#pragma unroll
      for (int mf = 0; mf < 4; ++mf)
#pragma unroll
        for (int nf = 0; nf < 4; ++nf)
          acc[mf][nf] = __builtin_amdgcn_mfma_f32_16x16x32_bf16(
              fa[mf].b, fb[nf].b, acc[mf][nf], 0, 0, 0);
    }
  }

  const int rbase = (lane >> 4) * 4, cbase = lane & 15;
#pragma unroll
  for (int mf = 0; mf < 4; ++mf) {
#pragma unroll
    for (int nf = 0; nf < 4; ++nf) {
      const int gcol = n0 + woffN + nf * 16 + cbase;
      float bn = (BIASMODE == 1) ? bias[gcol] : 0.f;
#pragma unroll
      for (int r = 0; r < 4; ++r) {
        const int grow = m0 + woffM + mf * 16 + rbase + r;
        const size_t idx = (size_t)zb * sC + (size_t)grow * ldc + gcol;
        float v = acc[mf][nf][r];
        if constexpr (BIASMODE == 2) v += bias[grow]; else v += bn;
        if constexpr (OUTMODE == 0) {
          ((short*)Cptr)[idx] = f2bs(v);
        } else if constexpr (OUTMODE == 1) {
          ((float*)Cptr)[idx] = v;
        } else if constexpr (OUTMODE == 2) {
          ((float*)Cptr)[idx] = 1.0f / (1.0f + __expf(-v * scale));
        } else {
          float p = 1.0f / (1.0f + __expf(-v * scale));
          ((float*)Cptr)[idx] = p;
          C2p[idx] = f2bs(p);
        }
      }
    }
  }
}

extern "C" void kernel_launch(void* const* d_in, const int* in_sizes, int n_in,
                              void* d_out, int out_size, void* d_ws, size_t ws_size,
                              hipStream_t stream) {
  const float* in1 = (const float*)d_in[0];   // [16][512][2048]
  const float* in2 = (const float*)d_in[1];   // [16][768][1024]
  const float* Wq1 = (const float*)d_in[2];  const float* bq1 = (const float*)d_in[3];
  const float* Wk1 = (const float*)d_in[4];  const float* bk1 = (const float*)d_in[5];
  const float* Wv1 = (const float*)d_in[6];  const float* bv1 = (const float*)d_in[7];
  const float* Wq2 = (const float*)d_in[8];  const float* bq2 = (const float*)d_in[9];
  const float* Wk2 = (const float*)d_in[10]; const float* bk2 = (const float*)d_in[11];
  const float* Wv2 = (const float*)d_in[12]; const float* bv2 = (const float*)d_in[13];

  float* out = (float*)d_out;
  float* ctx2   = out;                                      // [16][2048][512]
  float* probs2 = out + (size_t)16 * 2048 * 512;            // [16][2048][1024]
  float* ctx1   = probs2 + (size_t)16 * 2048 * 1024;        // [16][1024][512]
  float* probs1 = ctx1 + (size_t)16 * 1024 * 512;           // [16][1024][2048]

  char* ws = (char*)d_ws;
  constexpr size_t O_WQ1T = 0;
  constexpr size_t O_WK1T = O_WQ1T + (size_t)512 * 512 * 2;
  constexpr size_t O_WV1T = O_WK1T + (size_t)512 * 512 * 2;
  constexpr size_t O_WQ2T = O_WV1T + (size_t)512 * 512 * 2;
  constexpr size_t O_WK2T = O_WQ2T + (size_t)768 * 512 * 2;
  constexpr size_t O_WV2T = O_WK2T + (size_t)768 * 512 * 2;
  constexpr size_t O_B1   = O_WV2T + (size_t)768 * 512 * 2;
  constexpr size_t O_B2   = O_B1 + 4096;
  constexpr size_t O_QK1  = O_B2 + 4096;                          // [32768][1024]
  constexpr size_t O_V1T  = O_QK1 + (size_t)32768 * 1024 * 2;     // [16][512][2048]
  constexpr size_t O_QK2  = O_V1T + (size_t)16 * 512 * 2048 * 2;  // [16384][1024]
  constexpr size_t O_V2T  = O_QK2 + (size_t)16384 * 1024 * 2;     // [16][512][1024]
  constexpr size_t O_X1B  = O_V2T + (size_t)16 * 512 * 1024 * 2;  // [32768][512]
  constexpr size_t O_X2B  = O_X1B + (size_t)32768 * 512 * 2;      // [16384][768]
  constexpr size_t O_PB1  = O_X2B + (size_t)16384 * 768 * 2;      // bf16 probs1
  constexpr size_t O_PB2  = O_PB1 + (size_t)16 * 1024 * 2048 * 2; // bf16 probs2
  constexpr size_t NEED_A = O_PB2 + (size_t)16 * 2048 * 1024 * 2;
  constexpr size_t NEED_B = O_PB1;

  short* wq1t = (short*)(ws + O_WQ1T);
  short* wk1t = (short*)(ws + O_WK1T);
  short* wv1t = (short*)(ws + O_WV1T);
  short* wq2t = (short*)(ws + O_WQ2T);
  short* wk2t = (short*)(ws + O_WK2T);
  short* wv2t = (short*)(ws + O_WV2T);
  float* b1c  = (float*)(ws + O_B1);
  float* b2c  = (float*)(ws + O_B2);
  short* qk1  = (short*)(ws + O_QK1);
  short* v1t  = (short*)(ws + O_V1T);
  short* qk2  = (short*)(ws + O_QK2);
  short* v2t  = (short*)(ws + O_V2T);
  short* x1b  = (short*)(ws + O_X1B);
  short* x2b  = (short*)(ws + O_X2B);
  short* pb1  = (short*)(ws + O_PB1);
  short* pb2  = (short*)(ws + O_PB2);

  const bool tierA = ws_size >= NEED_A;
  const bool tierB = ws_size >= NEED_B;
  if (!tierB) { x1b = (short*)probs1; x2b = (short*)probs2; }

  dim3 blk256(256);
  dim3 blkT(32, 8);

  // ---- stage 0 ----
  transpose_cvt<<<dim3(64, 8, 16), blkT, 0, stream>>>(in1, x1b, 512, 2048);
  transpose_cvt<<<dim3(32, 12, 16), blkT, 0, stream>>>(in2, x2b, 768, 1024);
  prep_weights<<<dim3(16, 12, 7), blkT, 0, stream>>>(
      Wq1, Wk1, Wv1, Wq2, Wk2, Wv2, wq1t, wk1t, wv1t, wq2t, wk2t, wv2t,
      bq1, bk1, bq2, bk2, b1c, b2c);

  const float scale = 0.04419417382415922f;  // 1/sqrt(512)
  const short* q1p = qk1;        // lda 1024
  const short* k1p = qk1 + 512;
  const short* q2p = qk2;
  const short* k2p = qk2 + 512;

  if (tierA) {
    // ---- stage 1: projections ----
    gemm_p<0, 1><<<dim3(8, 256, 1), blk256, 0, stream>>>(
        x1b, wq1t, b1c, qk1, nullptr, 512, 512, 512, 1024, 0, 0, 0, 1.f);
    gemm_p<0, 1><<<dim3(8, 128, 1), blk256, 0, stream>>>(
        x2b, wq2t, b2c, qk2, nullptr, 768, 768, 768, 1024, 0, 0, 0, 1.f);
    gemm_p<0, 2><<<dim3(16, 4, 16), blk256, 0, stream>>>(
        wv1t, x1b, bv1, v1t, nullptr, 512, 512, 512, 2048,
        0, (long long)2048 * 512, (long long)512 * 2048, 1.f);
    gemm_p<0, 2><<<dim3(8, 4, 16), blk256, 0, stream>>>(
        wv2t, x2b, bv2, v2t, nullptr, 768, 768, 768, 1024,
        0, (long long)1024 * 768, (long long)512 * 1024, 1.f);
    // ---- stage 2: scores + sigmoid (dual store f32 + bf16) ----
    gemm_p<3, 0><<<dim3(16, 8, 16), blk256, 0, stream>>>(
        q2p, k1p, nullptr, probs1, pb1, 512, 1024, 1024, 2048,
        (long long)1024 * 1024, (long long)2048 * 1024, (long long)1024 * 2048, scale);
    gemm_p<3, 0><<<dim3(8, 16, 16), blk256, 0, stream>>>(
        q1p, k2p, nullptr, probs2, pb2, 512, 1024, 1024, 1024,
        (long long)2048 * 1024, (long long)1024 * 1024, (long long)2048 * 1024, scale);
    // ---- stage 3: ctx = probs(bf16) @ v^T ----
    gemm_p<1, 0><<<dim3(4, 8, 16), blk256, 0, stream>>>(
        pb1, v1t, nullptr, ctx1, nullptr, 2048, 2048, 2048, 512,
        (long long)1024 * 2048, (long long)512 * 2048, (long long)1024 * 512, 1.f);
    gemm_p<1, 0><<<dim3(4, 16, 16), blk256, 0, stream>>>(
        pb2, v2t, nullptr, ctx2, nullptr, 1024, 1024, 1024, 512,
        (long long)2048 * 1024, (long long)512 * 1024, (long long)2048 * 512, 1.f);
  } else {
    gemm_bt<0, 1, 0><<<dim3(8, 256, 1), blk256, 0, stream>>>(
        x1b, wq1t, b1c, qk1, nullptr, 512, 512, 512, 1024, 0, 0, 0, 1.f);
    gemm_bt<0, 1, 0><<<dim3(8, 128, 1), blk256, 0, stream>>>(
        x2b, wq2t, b2c, qk2, nullptr, 768, 768, 768, 1024, 0, 0, 0, 1.f);
    gemm_bt<0, 2, 0><<<dim3(16, 4, 16), blk256, 0, stream>>>(
        wv1t, x1b, bv1, v1t, nullptr, 512, 512, 512, 2048,
        0, (long long)2048 * 512, (long long)512 * 2048, 1.f);
    gemm_bt<0, 2, 0><<<dim3(8, 4, 16), blk256, 0, stream>>>(
        wv2t, x2b, bv2, v2t, nullptr, 768, 768, 768, 1024,
        0, (long long)1024 * 768, (long long)512 * 1024, 1.f);
    gemm_bt<2, 0, 0><<<dim3(16, 8, 16), blk256, 0, stream>>>(
        q2p, k1p, nullptr, probs1, nullptr, 512, 1024, 1024, 2048,
        (long long)1024 * 1024, (long long)2048 * 1024, (long long)1024 * 2048, scale);
    gemm_bt<2, 0, 0><<<dim3(8, 16, 16), blk256, 0, stream>>>(
        q1p, k2p, nullptr, probs2, nullptr, 512, 1024, 1024, 1024,
        (long long)2048 * 1024, (long long)1024 * 1024, (long long)2048 * 1024, scale);
    gemm_bt<1, 0, 1><<<dim3(4, 8, 16), blk256, 0, stream>>>(
        probs1, v1t, nullptr, ctx1, nullptr, 2048, 2048, 2048, 512,
        (long long)1024 * 2048, (long long)512 * 2048, (long long)1024 * 512, 1.f);
    gemm_bt<1, 0, 1><<<dim3(4, 16, 16), blk256, 0, stream>>>(
        probs2, v2t, nullptr, ctx2, nullptr, 1024, 1024, 1024, 512,
        (long long)2048 * 1024, (long long)512 * 1024, (long long)2048 * 512, 1.f);
  }
}

// Round 4
// 485.126 us; speedup vs baseline: 1.2434x; 1.1154x over previous
//
#include <hip/hip_runtime.h>
#include <hip/hip_bf16.h>

#define DEVFN __device__ __forceinline__

typedef __attribute__((ext_vector_type(4))) float f32x4;
typedef __attribute__((ext_vector_type(8))) short s16x8;
typedef __attribute__((ext_vector_type(2))) short s16x2;
typedef __attribute__((ext_vector_type(8))) __bf16 bf16x8;

union FragU { s16x8 s; bf16x8 b; };

DEVFN short f2bs(float x) {
  union { __hip_bfloat16 h; short s; } u;
  u.h = __float2bfloat16(x);
  return u.s;
}

DEVFN void gload16(const void* g, void* l) {
  __builtin_amdgcn_global_load_lds(
      (const __attribute__((address_space(1))) void*)g,
      (__attribute__((address_space(3))) void*)l, 16, 0, 0);
}

// in: [Z][C][L] f32 -> out: [Z][L][C] bf16. Block (32,8): C-tile 64, L-tile 32.
__global__ __launch_bounds__(256) void transpose_cvt(
    const float* __restrict__ in, short* __restrict__ out, int C, int L) {
  __shared__ float tile[64][33];
  const int l0 = blockIdx.x * 32, c0 = blockIdx.y * 64;
  const size_t base = (size_t)blockIdx.z * C * L;
  const int tx = threadIdx.x, ty = threadIdx.y;
#pragma unroll
  for (int i = ty; i < 64; i += 8)
    tile[i][tx] = in[base + (size_t)(c0 + i) * L + l0 + tx];
  __syncthreads();
#pragma unroll
  for (int i = ty; i < 32; i += 8) {
    s16x2 v;
    v[0] = f2bs(tile[2 * tx][i]);
    v[1] = f2bs(tile[2 * tx + 1][i]);
    *(s16x2*)&out[base + (size_t)(l0 + i) * C + c0 + 2 * tx] = v;
  }
}

// All six weight transposes + both bias concats, one launch.
__global__ __launch_bounds__(256) void prep_weights(
    const float* __restrict__ Wq1, const float* __restrict__ Wk1,
    const float* __restrict__ Wv1, const float* __restrict__ Wq2,
    const float* __restrict__ Wk2, const float* __restrict__ Wv2,
    short* wq1t, short* wk1t, short* wv1t,
    short* wq2t, short* wk2t, short* wv2t,
    const float* __restrict__ bq1, const float* __restrict__ bk1,
    const float* __restrict__ bq2, const float* __restrict__ bk2,
    float* b1c, float* b2c) {
  const int z = blockIdx.z;
  if (z == 6) {
    if (blockIdx.y != 0 || blockIdx.x >= 8) return;
    const int bx = blockIdx.x;
    const int tid = threadIdx.y * 32 + threadIdx.x;
    const int i = (bx & 3) * 256 + tid;
    const float* s = (bx < 4) ? ((i < 512) ? bq1 : bk1)
                              : ((i < 512) ? bq2 : bk2);
    float* d = (bx < 4) ? b1c : b2c;
    d[i] = s[i & 511];
    return;
  }
  const float* W; short* O; int C;
  switch (z) {
    case 0: W = Wq1; O = wq1t; C = 512; break;
    case 1: W = Wk1; O = wk1t; C = 512; break;
    case 2: W = Wv1; O = wv1t; C = 512; break;
    case 3: W = Wq2; O = wq2t; C = 768; break;
    case 4: W = Wk2; O = wk2t; C = 768; break;
    default: W = Wv2; O = wv2t; C = 768; break;
  }
  if (blockIdx.y * 64 >= (unsigned)C) return;
  const int L = 512;
  __shared__ float tile[64][33];
  const int l0 = blockIdx.x * 32, c0 = blockIdx.y * 64;
  const int tx = threadIdx.x, ty = threadIdx.y;
#pragma unroll
  for (int i = ty; i < 64; i += 8)
    tile[i][tx] = W[(size_t)(c0 + i) * L + l0 + tx];
  __syncthreads();
#pragma unroll
  for (int i = ty; i < 32; i += 8) {
    s16x2 v;
    v[0] = f2bs(tile[2 * tx][i]);
    v[1] = f2bs(tile[2 * tx + 1][i]);
    *(s16x2*)&O[(size_t)(l0 + i) * C + c0 + 2 * tx] = v;
  }
}

// ---------------------------------------------------------------------------
// Deep-pipelined 256x256 GEMM: C[m][n] = sum_k A[m][k]*Bt[n][k] (+bias).
// 8 waves (2Mx4N), per-wave 128x64 (acc[8][4]). BK=32. 4 LDS buffers of
// 32KB (A 16KB + B 16KB each) = 128 KiB. Prefetch depth 3; steady-state
// s_waitcnt vmcnt(8) (never 0 until tail); one barrier per K-step.
// LDS layout per operand tile (bijective, conflict-free for frag reads):
//   byte(r, cb) = (r>>1)*128 + (r&1)*64 + (cb ^ (((r>>1)&3)<<4)),
// staged with linear LDS dest + inverse-permuted per-lane global source.
// OUTMODE: 0=bf16, 1=f32, 2=sigmoid f32, 3=sigmoid f32 + bf16 to C2p
// BIASMODE: 0 none, 1 per-n, 2 per-m.
// ---------------------------------------------------------------------------
template <int OUTMODE, int BIASMODE>
__global__ __launch_bounds__(512, 2) void gemm8(
    const short* __restrict__ Ap, const short* __restrict__ Btp,
    const float* __restrict__ bias, void* __restrict__ Cptr,
    short* __restrict__ C2p,
    int K, int lda, int ldb, int ldc,
    long long sA, long long sB, long long sC, float scale) {
  __shared__ __align__(16) char smem[4 * 32768];
  const int tid = threadIdx.x;
  const int lane = tid & 63, wid = tid >> 6;
  const int wm = wid >> 2, wn = wid & 3;
  const int zb = blockIdx.z;
  const int m0 = blockIdx.y * 256, n0 = blockIdx.x * 256;
  const char* Ab = (const char*)(Ap + (size_t)zb * sA);
  const char* Bb = (const char*)(Btp + (size_t)zb * sB);
  const size_t lda2 = (size_t)lda * 2, ldb2 = (size_t)ldb * 2;

  // Staging: dest d = i*8192 + tid*16 (linear). Inverse-map to (row, colbyte):
  int s_r[2], s_cb[2];
#pragma unroll
  for (int i = 0; i < 2; ++i) {
    const int d = i * 8192 + tid * 16;
    const int line = d >> 7, half = (d >> 6) & 1, q = d & 63;
    s_r[i] = line * 2 + half;
    s_cb[i] = q ^ ((line & 3) << 4);
  }

  f32x4 acc[8][4] = {};
  const int frow = lane & 15, fkg = lane >> 4;

  int ra[8], rb[4];
#pragma unroll
  for (int mf = 0; mf < 8; ++mf) {
    const int R = wm * 128 + mf * 16 + frow;
    ra[mf] = (R >> 1) * 128 + (R & 1) * 64 + ((fkg * 16) ^ (((R >> 1) & 3) << 4));
  }
#pragma unroll
  for (int nf = 0; nf < 4; ++nf) {
    const int R = wn * 64 + nf * 16 + frow;
    rb[nf] = (R >> 1) * 128 + (R & 1) * 64 + ((fkg * 16) ^ (((R >> 1) & 3) << 4));
  }

  const int NT = K >> 5;

#define STAGE8(t)                                                        \
  {                                                                      \
    char* base_ = smem + ((t) & 3) * 32768;                              \
    const size_t kb_ = (size_t)(t) * 64;                                 \
    _Pragma("unroll")                                                    \
    for (int i = 0; i < 2; ++i) {                                        \
      gload16(Ab + (size_t)(m0 + s_r[i]) * lda2 + kb_ + s_cb[i],         \
              base_ + i * 8192 + tid * 16);                              \
      gload16(Bb + (size_t)(n0 + s_r[i]) * ldb2 + kb_ + s_cb[i],         \
              base_ + 16384 + i * 8192 + tid * 16);                      \
    }                                                                    \
  }

  STAGE8(0);
  if (NT > 1) STAGE8(1);
  if (NT > 2) STAGE8(2);
  if (NT > 2)      asm volatile("s_waitcnt vmcnt(8)" ::: "memory");
  else if (NT > 1) asm volatile("s_waitcnt vmcnt(4)" ::: "memory");
  else             asm volatile("s_waitcnt vmcnt(0)" ::: "memory");
  __builtin_amdgcn_sched_barrier(0);
  __builtin_amdgcn_s_barrier();
  __builtin_amdgcn_sched_barrier(0);

  for (int t = 0; t < NT; ++t) {
    if (t + 3 < NT) STAGE8(t + 3);
    const char* la = smem + (t & 3) * 32768;
    const char* lb = la + 16384;
    FragU fa[8], fb[4];
#pragma unroll
    for (int mf = 0; mf < 8; ++mf) fa[mf].s = *(const s16x8*)(la + ra[mf]);
#pragma unroll
    for (int nf = 0; nf < 4; ++nf) fb[nf].s = *(const s16x8*)(lb + rb[nf]);
    __builtin_amdgcn_s_setprio(1);
#pragma unroll
    for (int mf = 0; mf < 8; ++mf)
#pragma unroll
      for (int nf = 0; nf < 4; ++nf)
        acc[mf][nf] = __builtin_amdgcn_mfma_f32_16x16x32_bf16(
            fa[mf].b, fb[nf].b, acc[mf][nf], 0, 0, 0);
    __builtin_amdgcn_s_setprio(0);
    if (t + 3 < NT) {
      asm volatile("s_waitcnt vmcnt(8)" ::: "memory");
    } else if (t + 2 < NT) {
      asm volatile("s_waitcnt vmcnt(4)" ::: "memory");
    } else if (t + 1 < NT) {
      asm volatile("s_waitcnt vmcnt(0)" ::: "memory");
    } else {
      break;  // last iteration: no further reads of LDS
    }
    __builtin_amdgcn_sched_barrier(0);
    __builtin_amdgcn_s_barrier();
    __builtin_amdgcn_sched_barrier(0);
  }
#undef STAGE8

  const int rbase = (lane >> 4) * 4, cbase = lane & 15;
#pragma unroll
  for (int mf = 0; mf < 8; ++mf) {
#pragma unroll
    for (int nf = 0; nf < 4; ++nf) {
      const int gcol = n0 + wn * 64 + nf * 16 + cbase;
      float bn = (BIASMODE == 1) ? bias[gcol] : 0.f;
#pragma unroll
      for (int r = 0; r < 4; ++r) {
        const int grow = m0 + wm * 128 + mf * 16 + rbase + r;
        const size_t idx = (size_t)zb * sC + (size_t)grow * ldc + gcol;
        float v = acc[mf][nf][r];
        if constexpr (BIASMODE == 2) v += bias[grow]; else v += bn;
        if constexpr (OUTMODE == 0) {
          ((short*)Cptr)[idx] = f2bs(v);
        } else if constexpr (OUTMODE == 1) {
          ((float*)Cptr)[idx] = v;
        } else if constexpr (OUTMODE == 2) {
          ((float*)Cptr)[idx] = 1.0f / (1.0f + __expf(-v * scale));
        } else {
          float p = 1.0f / (1.0f + __expf(-v * scale));
          ((float*)Cptr)[idx] = p;
          C2p[idx] = f2bs(p);
        }
      }
    }
  }
}

// ---------------------------------------------------------------------------
// Fallback (tierB only): gload-staged 128x128 BK=64 GEMM, AF32 supported.
// ---------------------------------------------------------------------------
template <int OUTMODE, int BIASMODE, int AF32>
__global__ __launch_bounds__(256) void gemm_bt(
    const void* __restrict__ Aptr, const short* __restrict__ Btp,
    const float* __restrict__ bias, void* __restrict__ Cptr,
    short* __restrict__ C2p,
    int K, int lda, int ldb, int ldc,
    long long sA, long long sB, long long sC, float scale) {
  __shared__ __align__(16) short lsA[128 * 64];
  __shared__ __align__(16) short lsB[128 * 64];
  const int tid = threadIdx.x;
  const int lane = tid & 63, wid = tid >> 6;
  const int zb = blockIdx.z;
  const int m0 = blockIdx.y * 128, n0 = blockIdx.x * 128;
  const short* Ab = AF32 ? nullptr : (const short*)Aptr + (size_t)zb * sA;
  const float* Af = AF32 ? (const float*)Aptr + (size_t)zb * sA : nullptr;
  const short* Bt = Btp + (size_t)zb * sB;

  f32x4 acc[4][4] = {};
  const int woffM = (wid >> 1) * 64, woffN = (wid & 1) * 64;
  const int frow = lane & 15, fkg = lane >> 4;

  for (int k0 = 0; k0 < K; k0 += 64) {
    if (k0) __syncthreads();
    if constexpr (!AF32) {
#pragma unroll
      for (int i = 0; i < 4; ++i) {
        const int f = i * 4096 + tid * 16;
        const int row = f >> 7, colb = f & 127;
        gload16((const char*)Ab + ((size_t)(m0 + row) * lda + k0) * 2 + colb,
                (char*)lsA + f);
      }
    } else {
#pragma unroll
      for (int i = 0; i < 8; ++i) {
        int f = tid + i * 256;
        int row = f >> 4, c4 = f & 15;
        f32x4 v = *(const f32x4*)&Af[(size_t)(m0 + row) * lda + k0 + c4 * 4];
        union { short s[4]; unsigned long long q; } cv;
#pragma unroll
        for (int j = 0; j < 4; ++j) cv.s[j] = f2bs(v[j]);
        *(unsigned long long*)&lsA[row * 64 + c4 * 4] = cv.q;
      }
    }
#pragma unroll
    for (int i = 0; i < 4; ++i) {
      const int f = i * 4096 + tid * 16;
      const int row = f >> 7, colb = f & 127;
      gload16((const char*)Bt + ((size_t)(n0 + row) * ldb + k0) * 2 + colb,
              (char*)lsB + f);
    }
    __syncthreads();
#pragma unroll
    for (int kk = 0; kk < 2; ++kk) {
      const int kb = kk * 32 + fkg * 8;
      FragU fa[4], fb[4];
#pragma unroll
      for (int mf = 0; mf < 4; ++mf)
        fa[mf].s = *(const s16x8*)&lsA[(woffM + mf * 16 + frow) * 64 + kb];
#pragma unroll
      for (int nf = 0; nf < 4; ++nf)
        fb[nf].s = *(const s16x8*)&lsB[(woffN + nf * 16 + frow) * 64 + kb];
#pragma unroll
      for (int mf = 0; mf < 4; ++mf)
#pragma unroll
        for (int nf = 0; nf < 4; ++nf)
          acc[mf][nf] = __builtin_amdgcn_mfma_f32_16x16x32_bf16(
              fa[mf].b, fb[nf].b, acc[mf][nf], 0, 0, 0);
    }
  }

  const int rbase = (lane >> 4) * 4, cbase = lane & 15;
#pragma unroll
  for (int mf = 0; mf < 4; ++mf) {
#pragma unroll
    for (int nf = 0; nf < 4; ++nf) {
      const int gcol = n0 + woffN + nf * 16 + cbase;
      float bn = (BIASMODE == 1) ? bias[gcol] : 0.f;
#pragma unroll
      for (int r = 0; r < 4; ++r) {
        const int grow = m0 + woffM + mf * 16 + rbase + r;
        const size_t idx = (size_t)zb * sC + (size_t)grow * ldc + gcol;
        float v = acc[mf][nf][r];
        if constexpr (BIASMODE == 2) v += bias[grow]; else v += bn;
        if constexpr (OUTMODE == 0) {
          ((short*)Cptr)[idx] = f2bs(v);
        } else if constexpr (OUTMODE == 1) {
          ((float*)Cptr)[idx] = v;
        } else if constexpr (OUTMODE == 2) {
          ((float*)Cptr)[idx] = 1.0f / (1.0f + __expf(-v * scale));
        } else {
          float p = 1.0f / (1.0f + __expf(-v * scale));
          ((float*)Cptr)[idx] = p;
          C2p[idx] = f2bs(p);
        }
      }
    }
  }
}

extern "C" void kernel_launch(void* const* d_in, const int* in_sizes, int n_in,
                              void* d_out, int out_size, void* d_ws, size_t ws_size,
                              hipStream_t stream) {
  const float* in1 = (const float*)d_in[0];   // [16][512][2048]
  const float* in2 = (const float*)d_in[1];   // [16][768][1024]
  const float* Wq1 = (const float*)d_in[2];  const float* bq1 = (const float*)d_in[3];
  const float* Wk1 = (const float*)d_in[4];  const float* bk1 = (const float*)d_in[5];
  const float* Wv1 = (const float*)d_in[6];  const float* bv1 = (const float*)d_in[7];
  const float* Wq2 = (const float*)d_in[8];  const float* bq2 = (const float*)d_in[9];
  const float* Wk2 = (const float*)d_in[10]; const float* bk2 = (const float*)d_in[11];
  const float* Wv2 = (const float*)d_in[12]; const float* bv2 = (const float*)d_in[13];

  float* out = (float*)d_out;
  float* ctx2   = out;                                      // [16][2048][512]
  float* probs2 = out + (size_t)16 * 2048 * 512;            // [16][2048][1024]
  float* ctx1   = probs2 + (size_t)16 * 2048 * 1024;        // [16][1024][512]
  float* probs1 = ctx1 + (size_t)16 * 1024 * 512;           // [16][1024][2048]

  char* ws = (char*)d_ws;
  constexpr size_t O_WQ1T = 0;
  constexpr size_t O_WK1T = O_WQ1T + (size_t)512 * 512 * 2;
  constexpr size_t O_WV1T = O_WK1T + (size_t)512 * 512 * 2;
  constexpr size_t O_WQ2T = O_WV1T + (size_t)512 * 512 * 2;
  constexpr size_t O_WK2T = O_WQ2T + (size_t)768 * 512 * 2;
  constexpr size_t O_WV2T = O_WK2T + (size_t)768 * 512 * 2;
  constexpr size_t O_B1   = O_WV2T + (size_t)768 * 512 * 2;
  constexpr size_t O_B2   = O_B1 + 4096;
  constexpr size_t O_QK1  = O_B2 + 4096;                          // [32768][1024]
  constexpr size_t O_V1T  = O_QK1 + (size_t)32768 * 1024 * 2;     // [16][512][2048]
  constexpr size_t O_QK2  = O_V1T + (size_t)16 * 512 * 2048 * 2;  // [16384][1024]
  constexpr size_t O_V2T  = O_QK2 + (size_t)16384 * 1024 * 2;     // [16][512][1024]
  constexpr size_t O_X1B  = O_V2T + (size_t)16 * 512 * 1024 * 2;  // [32768][512]
  constexpr size_t O_X2B  = O_X1B + (size_t)32768 * 512 * 2;      // [16384][768]
  constexpr size_t O_PB1  = O_X2B + (size_t)16384 * 768 * 2;      // bf16 probs1
  constexpr size_t O_PB2  = O_PB1 + (size_t)16 * 1024 * 2048 * 2; // bf16 probs2
  constexpr size_t NEED_A = O_PB2 + (size_t)16 * 2048 * 1024 * 2;
  constexpr size_t NEED_B = O_PB1;

  short* wq1t = (short*)(ws + O_WQ1T);
  short* wk1t = (short*)(ws + O_WK1T);
  short* wv1t = (short*)(ws + O_WV1T);
  short* wq2t = (short*)(ws + O_WQ2T);
  short* wk2t = (short*)(ws + O_WK2T);
  short* wv2t = (short*)(ws + O_WV2T);
  float* b1c  = (float*)(ws + O_B1);
  float* b2c  = (float*)(ws + O_B2);
  short* qk1  = (short*)(ws + O_QK1);
  short* v1t  = (short*)(ws + O_V1T);
  short* qk2  = (short*)(ws + O_QK2);
  short* v2t  = (short*)(ws + O_V2T);
  short* x1b  = (short*)(ws + O_X1B);
  short* x2b  = (short*)(ws + O_X2B);
  short* pb1  = (short*)(ws + O_PB1);
  short* pb2  = (short*)(ws + O_PB2);

  const bool tierA = ws_size >= NEED_A;
  const bool tierB = ws_size >= NEED_B;
  if (!tierB) { x1b = (short*)probs1; x2b = (short*)probs2; }

  dim3 blk256(256), blk512(512);
  dim3 blkT(32, 8);

  // ---- stage 0 ----
  transpose_cvt<<<dim3(64, 8, 16), blkT, 0, stream>>>(in1, x1b, 512, 2048);
  transpose_cvt<<<dim3(32, 12, 16), blkT, 0, stream>>>(in2, x2b, 768, 1024);
  prep_weights<<<dim3(16, 12, 7), blkT, 0, stream>>>(
      Wq1, Wk1, Wv1, Wq2, Wk2, Wv2, wq1t, wk1t, wv1t, wq2t, wk2t, wv2t,
      bq1, bk1, bq2, bk2, b1c, b2c);

  const float scale = 0.04419417382415922f;  // 1/sqrt(512)
  const short* q1p = qk1;        // lda 1024
  const short* k1p = qk1 + 512;
  const short* q2p = qk2;
  const short* k2p = qk2 + 512;

  if (tierA) {
    // ---- stage 1: projections ----
    gemm8<0, 1><<<dim3(4, 128, 1), blk512, 0, stream>>>(
        x1b, wq1t, b1c, qk1, nullptr, 512, 512, 512, 1024, 0, 0, 0, 1.f);
    gemm8<0, 1><<<dim3(4, 64, 1), blk512, 0, stream>>>(
        x2b, wq2t, b2c, qk2, nullptr, 768, 768, 768, 1024, 0, 0, 0, 1.f);
    gemm8<0, 2><<<dim3(8, 2, 16), blk512, 0, stream>>>(
        wv1t, x1b, bv1, v1t, nullptr, 512, 512, 512, 2048,
        0, (long long)2048 * 512, (long long)512 * 2048, 1.f);
    gemm8<0, 2><<<dim3(4, 2, 16), blk512, 0, stream>>>(
        wv2t, x2b, bv2, v2t, nullptr, 768, 768, 768, 1024,
        0, (long long)1024 * 768, (long long)512 * 1024, 1.f);
    // ---- stage 2: scores + sigmoid (dual store f32 + bf16) ----
    gemm8<3, 0><<<dim3(8, 4, 16), blk512, 0, stream>>>(
        q2p, k1p, nullptr, probs1, pb1, 512, 1024, 1024, 2048,
        (long long)1024 * 1024, (long long)2048 * 1024, (long long)1024 * 2048, scale);
    gemm8<3, 0><<<dim3(4, 8, 16), blk512, 0, stream>>>(
        q1p, k2p, nullptr, probs2, pb2, 512, 1024, 1024, 1024,
        (long long)2048 * 1024, (long long)1024 * 1024, (long long)2048 * 1024, scale);
    // ---- stage 3: ctx = probs(bf16) @ v^T ----
    gemm8<1, 0><<<dim3(2, 4, 16), blk512, 0, stream>>>(
        pb1, v1t, nullptr, ctx1, nullptr, 2048, 2048, 2048, 512,
        (long long)1024 * 2048, (long long)512 * 2048, (long long)1024 * 512, 1.f);
    gemm8<1, 0><<<dim3(2, 8, 16), blk512, 0, stream>>>(
        pb2, v2t, nullptr, ctx2, nullptr, 1024, 1024, 1024, 512,
        (long long)2048 * 1024, (long long)512 * 1024, (long long)2048 * 512, 1.f);
  } else {
    gemm_bt<0, 1, 0><<<dim3(8, 256, 1), blk256, 0, stream>>>(
        x1b, wq1t, b1c, qk1, nullptr, 512, 512, 512, 1024, 0, 0, 0, 1.f);
    gemm_bt<0, 1, 0><<<dim3(8, 128, 1), blk256, 0, stream>>>(
        x2b, wq2t, b2c, qk2, nullptr, 768, 768, 768, 1024, 0, 0, 0, 1.f);
    gemm_bt<0, 2, 0><<<dim3(16, 4, 16), blk256, 0, stream>>>(
        wv1t, x1b, bv1, v1t, nullptr, 512, 512, 512, 2048,
        0, (long long)2048 * 512, (long long)512 * 2048, 1.f);
    gemm_bt<0, 2, 0><<<dim3(8, 4, 16), blk256, 0, stream>>>(
        wv2t, x2b, bv2, v2t, nullptr, 768, 768, 768, 1024,
        0, (long long)1024 * 768, (long long)512 * 1024, 1.f);
    gemm_bt<2, 0, 0><<<dim3(16, 8, 16), blk256, 0, stream>>>(
        q2p, k1p, nullptr, probs1, nullptr, 512, 1024, 1024, 2048,
        (long long)1024 * 1024, (long long)2048 * 1024, (long long)1024 * 2048, scale);
    gemm_bt<2, 0, 0><<<dim3(8, 16, 16), blk256, 0, stream>>>(
        q1p, k2p, nullptr, probs2, nullptr, 512, 1024, 1024, 1024,
        (long long)2048 * 1024, (long long)1024 * 1024, (long long)2048 * 1024, scale);
    gemm_bt<1, 0, 1><<<dim3(4, 8, 16), blk256, 0, stream>>>(
        probs1, v1t, nullptr, ctx1, nullptr, 2048, 2048, 2048, 512,
        (long long)1024 * 2048, (long long)512 * 2048, (long long)1024 * 512, 1.f);
    gemm_bt<1, 0, 1><<<dim3(4, 16, 16), blk256, 0, stream>>>(
        probs2, v2t, nullptr, ctx2, nullptr, 1024, 1024, 1024, 512,
        (long long)2048 * 1024, (long long)512 * 1024, (long long)2048 * 512, 1.f);
  }
}

// Round 5
// 468.783 us; speedup vs baseline: 1.2868x; 1.0349x over previous
//
#include <hip/hip_runtime.h>
#include <hip/hip_bf16.h>

#define DEVFN __device__ __forceinline__

typedef __attribute__((ext_vector_type(4))) float f32x4;
typedef __attribute__((ext_vector_type(8))) short s16x8;
typedef __attribute__((ext_vector_type(2))) short s16x2;
typedef __attribute__((ext_vector_type(8))) __bf16 bf16x8;

union FragU { s16x8 s; bf16x8 b; };

DEVFN short f2bs(float x) {
  union { __hip_bfloat16 h; short s; } u;
  u.h = __float2bfloat16(x);
  return u.s;
}

DEVFN void gload16(const void* g, void* l) {
  __builtin_amdgcn_global_load_lds(
      (const __attribute__((address_space(1))) void*)g,
      (__attribute__((address_space(3))) void*)l, 16, 0, 0);
}

template <int N> DEVFN void waitcnt_vm() {
  if constexpr (N == 0) asm volatile("s_waitcnt vmcnt(0)" ::: "memory");
  else if constexpr (N == 3) asm volatile("s_waitcnt vmcnt(3)" ::: "memory");
  else if constexpr (N == 4) asm volatile("s_waitcnt vmcnt(4)" ::: "memory");
  else if constexpr (N == 6) asm volatile("s_waitcnt vmcnt(6)" ::: "memory");
  else if constexpr (N == 8) asm volatile("s_waitcnt vmcnt(8)" ::: "memory");
  else static_assert(N == 0, "unsupported vmcnt");
}

// in: [Z][C][L] f32 -> out: [Z][L][C] bf16. Block (32,8): C-tile 64, L-tile 32.
__global__ __launch_bounds__(256) void transpose_cvt(
    const float* __restrict__ in, short* __restrict__ out, int C, int L) {
  __shared__ float tile[64][33];
  const int l0 = blockIdx.x * 32, c0 = blockIdx.y * 64;
  const size_t base = (size_t)blockIdx.z * C * L;
  const int tx = threadIdx.x, ty = threadIdx.y;
#pragma unroll
  for (int i = ty; i < 64; i += 8)
    tile[i][tx] = in[base + (size_t)(c0 + i) * L + l0 + tx];
  __syncthreads();
#pragma unroll
  for (int i = ty; i < 32; i += 8) {
    s16x2 v;
    v[0] = f2bs(tile[2 * tx][i]);
    v[1] = f2bs(tile[2 * tx + 1][i]);
    *(s16x2*)&out[base + (size_t)(l0 + i) * C + c0 + 2 * tx] = v;
  }
}

// All six weight transposes + both bias concats, one launch.
__global__ __launch_bounds__(256) void prep_weights(
    const float* __restrict__ Wq1, const float* __restrict__ Wk1,
    const float* __restrict__ Wv1, const float* __restrict__ Wq2,
    const float* __restrict__ Wk2, const float* __restrict__ Wv2,
    short* wq1t, short* wk1t, short* wv1t,
    short* wq2t, short* wk2t, short* wv2t,
    const float* __restrict__ bq1, const float* __restrict__ bk1,
    const float* __restrict__ bq2, const float* __restrict__ bk2,
    float* b1c, float* b2c) {
  const int z = blockIdx.z;
  if (z == 6) {
    if (blockIdx.y != 0 || blockIdx.x >= 8) return;
    const int bx = blockIdx.x;
    const int tid = threadIdx.y * 32 + threadIdx.x;
    const int i = (bx & 3) * 256 + tid;
    const float* s = (bx < 4) ? ((i < 512) ? bq1 : bk1)
                              : ((i < 512) ? bq2 : bk2);
    float* d = (bx < 4) ? b1c : b2c;
    d[i] = s[i & 511];
    return;
  }
  const float* W; short* O; int C;
  switch (z) {
    case 0: W = Wq1; O = wq1t; C = 512; break;
    case 1: W = Wk1; O = wk1t; C = 512; break;
    case 2: W = Wv1; O = wv1t; C = 512; break;
    case 3: W = Wq2; O = wq2t; C = 768; break;
    case 4: W = Wk2; O = wk2t; C = 768; break;
    default: W = Wv2; O = wv2t; C = 768; break;
  }
  if (blockIdx.y * 64 >= (unsigned)C) return;
  const int L = 512;
  __shared__ float tile[64][33];
  const int l0 = blockIdx.x * 32, c0 = blockIdx.y * 64;
  const int tx = threadIdx.x, ty = threadIdx.y;
#pragma unroll
  for (int i = ty; i < 64; i += 8)
    tile[i][tx] = W[(size_t)(c0 + i) * L + l0 + tx];
  __syncthreads();
#pragma unroll
  for (int i = ty; i < 32; i += 8) {
    s16x2 v;
    v[0] = f2bs(tile[2 * tx][i]);
    v[1] = f2bs(tile[2 * tx + 1][i]);
    *(s16x2*)&O[(size_t)(l0 + i) * C + c0 + 2 * tx] = v;
  }
}

// ---------------------------------------------------------------------------
// Deep-pipelined, phase-split GEMM: C[m][n] = sum_k A[m][k]*Bt[n][k] (+bias).
// Tile BM x 256, BM = MR*32 (MR=8 -> 256x256; MR=4 -> 128x256).
// 8 waves (2M x 4N); per-wave (MR*16) x 64 = acc[MR][4]. BK=32.
// 4 LDS buffers, prefetch depth 3; steady-state vmcnt(2*LPT); tail cascade.
// Two phases per K-step (m201 pattern): each phase = {stage-issue, ds_read
// half, barrier, lgkmcnt(0)+sched_barrier, setprio(1), 16*(MR/4) MFMA,
// setprio(0), barrier}. Staging/wait schedule identical to the verified R3
// schedule; phases only add barriers (no memory-ordering change).
// LDS layout per operand tile (bijective, conflict-reduced for frag reads):
//   byte(r, cb) = (r>>1)*128 + (r&1)*64 + (cb ^ (((r>>1)&3)<<4)),
// staged with linear LDS dest + inverse-permuted per-lane global source.
// Requires NT = K/32 >= 3 (all call sites have K >= 512).
// OUTMODE: 0=bf16, 1=f32, 2=sigmoid f32, 3=sigmoid f32 + bf16 to C2p
// BIASMODE: 0 none, 1 per-n, 2 per-m.
// ---------------------------------------------------------------------------
template <int OUTMODE, int BIASMODE, int MR>
__global__ __launch_bounds__(512, 2) void gemm8(
    const short* __restrict__ Ap, const short* __restrict__ Btp,
    const float* __restrict__ bias, void* __restrict__ Cptr,
    short* __restrict__ C2p,
    int K, int lda, int ldb, int ldc,
    long long sA, long long sB, long long sC, float scale) {
  constexpr int BM = MR * 32;
  constexpr int BN = 256;
  constexpr int LA = BM / 128;        // gloads/thread for A tile
  constexpr int LB = BN / 128;        // gloads/thread for B tile
  constexpr int LPT = LA + LB;
  constexpr int ABYTES = BM * 64;     // BM x 32k x 2B
  constexpr int BUFB = (BM + BN) * 64;
  constexpr int MH = MR / 2;
  __shared__ __align__(16) char smem[4 * BUFB];
  const int tid = threadIdx.x;
  const int lane = tid & 63, wid = tid >> 6;
  const int wm = wid >> 2, wn = wid & 3;
  const int zb = blockIdx.z;
  const int m0 = blockIdx.y * BM, n0 = blockIdx.x * BN;
  const char* Ab = (const char*)(Ap + (size_t)zb * sA);
  const char* Bb = (const char*)(Btp + (size_t)zb * sB);
  const size_t lda2 = (size_t)lda * 2, ldb2 = (size_t)ldb * 2;

  // Staging: dest d = j*8192 + tid*16 (linear). Inverse-map to (row, colbyte).
  int s_r[2], s_cb[2];
#pragma unroll
  for (int j = 0; j < 2; ++j) {
    const int d = j * 8192 + tid * 16;
    const int line = d >> 7;
    s_r[j] = line * 2 + ((d >> 6) & 1);
    s_cb[j] = (d & 63) ^ ((line & 3) << 4);
  }

  f32x4 acc[MR][4] = {};
  const int frow = lane & 15, fkg = lane >> 4;

  int ra[MR], rb[4];
#pragma unroll
  for (int mf = 0; mf < MR; ++mf) {
    const int R = wm * (MR * 16) + mf * 16 + frow;
    ra[mf] = (R >> 1) * 128 + (R & 1) * 64 + ((fkg * 16) ^ (((R >> 1) & 3) << 4));
  }
#pragma unroll
  for (int nf = 0; nf < 4; ++nf) {
    const int R = wn * 64 + nf * 16 + frow;
    rb[nf] = (R >> 1) * 128 + (R & 1) * 64 + ((fkg * 16) ^ (((R >> 1) & 3) << 4));
  }

  const int NT = K >> 5;

#define STAGE_A(t)                                                       \
  {                                                                      \
    char* base_ = smem + ((t) & 3) * BUFB;                               \
    const size_t kb_ = (size_t)(t) * 64;                                 \
    _Pragma("unroll")                                                    \
    for (int j = 0; j < LA; ++j)                                         \
      gload16(Ab + (size_t)(m0 + s_r[j]) * lda2 + kb_ + s_cb[j],         \
              base_ + j * 8192 + tid * 16);                              \
  }
#define STAGE_B(t)                                                       \
  {                                                                      \
    char* base_ = smem + ((t) & 3) * BUFB + ABYTES;                      \
    const size_t kb_ = (size_t)(t) * 64;                                 \
    _Pragma("unroll")                                                    \
    for (int j = 0; j < LB; ++j)                                         \
      gload16(Bb + (size_t)(n0 + s_r[j]) * ldb2 + kb_ + s_cb[j],         \
              base_ + j * 8192 + tid * 16);                              \
  }

  // prologue: 3 tiles in flight, wait for tile 0 (NT >= 3 guaranteed)
  STAGE_A(0); STAGE_B(0);
  STAGE_A(1); STAGE_B(1);
  STAGE_A(2); STAGE_B(2);
  waitcnt_vm<2 * LPT>();
  __builtin_amdgcn_sched_barrier(0);
  __builtin_amdgcn_s_barrier();
  __builtin_amdgcn_sched_barrier(0);

  for (int t = 0; t < NT; ++t) {
    const char* la = smem + (t & 3) * BUFB;
    const char* lb = la + ABYTES;
    FragU fa[MR], fb[4];
    // ---- phase 1: stage A(t+3) | read fa[0..MH), fb[0..4) | MFMA mf<MH ----
    if (t + 3 < NT) STAGE_A(t + 3);
#pragma unroll
    for (int mf = 0; mf < MH; ++mf) fa[mf].s = *(const s16x8*)(la + ra[mf]);
#pragma unroll
    for (int nf = 0; nf < 4; ++nf) fb[nf].s = *(const s16x8*)(lb + rb[nf]);
    __builtin_amdgcn_s_barrier();
    asm volatile("s_waitcnt lgkmcnt(0)" ::: "memory");
    __builtin_amdgcn_sched_barrier(0);
    __builtin_amdgcn_s_setprio(1);
#pragma unroll
    for (int mf = 0; mf < MH; ++mf)
#pragma unroll
      for (int nf = 0; nf < 4; ++nf)
        acc[mf][nf] = __builtin_amdgcn_mfma_f32_16x16x32_bf16(
            fa[mf].b, fb[nf].b, acc[mf][nf], 0, 0, 0);
    __builtin_amdgcn_s_setprio(0);
    __builtin_amdgcn_s_barrier();
    // ---- phase 2: stage B(t+3) | read fa[MH..MR) | MFMA mf>=MH ----
    if (t + 3 < NT) STAGE_B(t + 3);
#pragma unroll
    for (int mf = MH; mf < MR; ++mf) fa[mf].s = *(const s16x8*)(la + ra[mf]);
    __builtin_amdgcn_s_barrier();
    asm volatile("s_waitcnt lgkmcnt(0)" ::: "memory");
    __builtin_amdgcn_sched_barrier(0);
    __builtin_amdgcn_s_setprio(1);
#pragma unroll
    for (int mf = MH; mf < MR; ++mf)
#pragma unroll
      for (int nf = 0; nf < 4; ++nf)
        acc[mf][nf] = __builtin_amdgcn_mfma_f32_16x16x32_bf16(
            fa[mf].b, fb[nf].b, acc[mf][nf], 0, 0, 0);
    __builtin_amdgcn_s_setprio(0);
    // ---- end-of-iter wait (identical schedule to verified R3 kernel) ----
    if (t + 3 < NT) {
      waitcnt_vm<2 * LPT>();
    } else if (t + 2 < NT) {
      waitcnt_vm<LPT>();
    } else if (t + 1 < NT) {
      waitcnt_vm<0>();
    } else {
      break;  // last iteration: no further LDS reads
    }
    __builtin_amdgcn_sched_barrier(0);
    __builtin_amdgcn_s_barrier();
    __builtin_amdgcn_sched_barrier(0);
  }
#undef STAGE_A
#undef STAGE_B

  const int rbase = (lane >> 4) * 4, cbase = lane & 15;
#pragma unroll
  for (int mf = 0; mf < MR; ++mf) {
#pragma unroll
    for (int nf = 0; nf < 4; ++nf) {
      const int gcol = n0 + wn * 64 + nf * 16 + cbase;
      float bn = (BIASMODE == 1) ? bias[gcol] : 0.f;
#pragma unroll
      for (int r = 0; r < 4; ++r) {
        const int grow = m0 + wm * (MR * 16) + mf * 16 + rbase + r;
        const size_t idx = (size_t)zb * sC + (size_t)grow * ldc + gcol;
        float v = acc[mf][nf][r];
        if constexpr (BIASMODE == 2) v += bias[grow]; else v += bn;
        if constexpr (OUTMODE == 0) {
          ((short*)Cptr)[idx] = f2bs(v);
        } else if constexpr (OUTMODE == 1) {
          ((float*)Cptr)[idx] = v;
        } else if constexpr (OUTMODE == 2) {
          ((float*)Cptr)[idx] = 1.0f / (1.0f + __expf(-v * scale));
        } else {
          float p = 1.0f / (1.0f + __expf(-v * scale));
          ((float*)Cptr)[idx] = p;
          C2p[idx] = f2bs(p);
        }
      }
    }
  }
}

// ---------------------------------------------------------------------------
// Fallback (tierB only): gload-staged 128x128 BK=64 GEMM, AF32 supported.
// ---------------------------------------------------------------------------
template <int OUTMODE, int BIASMODE, int AF32>
__global__ __launch_bounds__(256) void gemm_bt(
    const void* __restrict__ Aptr, const short* __restrict__ Btp,
    const float* __restrict__ bias, void* __restrict__ Cptr,
    short* __restrict__ C2p,
    int K, int lda, int ldb, int ldc,
    long long sA, long long sB, long long sC, float scale) {
  __shared__ __align__(16) short lsA[128 * 64];
  __shared__ __align__(16) short lsB[128 * 64];
  const int tid = threadIdx.x;
  const int lane = tid & 63, wid = tid >> 6;
  const int zb = blockIdx.z;
  const int m0 = blockIdx.y * 128, n0 = blockIdx.x * 128;
  const short* Ab = AF32 ? nullptr : (const short*)Aptr + (size_t)zb * sA;
  const float* Af = AF32 ? (const float*)Aptr + (size_t)zb * sA : nullptr;
  const short* Bt = Btp + (size_t)zb * sB;

  f32x4 acc[4][4] = {};
  const int woffM = (wid >> 1) * 64, woffN = (wid & 1) * 64;
  const int frow = lane & 15, fkg = lane >> 4;

  for (int k0 = 0; k0 < K; k0 += 64) {
    if (k0) __syncthreads();
    if constexpr (!AF32) {
#pragma unroll
      for (int i = 0; i < 4; ++i) {
        const int f = i * 4096 + tid * 16;
        const int row = f >> 7, colb = f & 127;
        gload16((const char*)Ab + ((size_t)(m0 + row) * lda + k0) * 2 + colb,
                (char*)lsA + f);
      }
    } else {
#pragma unroll
      for (int i = 0; i < 8; ++i) {
        int f = tid + i * 256;
        int row = f >> 4, c4 = f & 15;
        f32x4 v = *(const f32x4*)&Af[(size_t)(m0 + row) * lda + k0 + c4 * 4];
        union { short s[4]; unsigned long long q; } cv;
#pragma unroll
        for (int j = 0; j < 4; ++j) cv.s[j] = f2bs(v[j]);
        *(unsigned long long*)&lsA[row * 64 + c4 * 4] = cv.q;
      }
    }
#pragma unroll
    for (int i = 0; i < 4; ++i) {
      const int f = i * 4096 + tid * 16;
      const int row = f >> 7, colb = f & 127;
      gload16((const char*)Bt + ((size_t)(n0 + row) * ldb + k0) * 2 + colb,
              (char*)lsB + f);
    }
    __syncthreads();
#pragma unroll
    for (int kk = 0; kk < 2; ++kk) {
      const int kb = kk * 32 + fkg * 8;
      FragU fa[4], fb[4];
#pragma unroll
      for (int mf = 0; mf < 4; ++mf)
        fa[mf].s = *(const s16x8*)&lsA[(woffM + mf * 16 + frow) * 64 + kb];
#pragma unroll
      for (int nf = 0; nf < 4; ++nf)
        fb[nf].s = *(const s16x8*)&lsB[(woffN + nf * 16 + frow) * 64 + kb];
#pragma unroll
      for (int mf = 0; mf < 4; ++mf)
#pragma unroll
        for (int nf = 0; nf < 4; ++nf)
          acc[mf][nf] = __builtin_amdgcn_mfma_f32_16x16x32_bf16(
              fa[mf].b, fb[nf].b, acc[mf][nf], 0, 0, 0);
    }
  }

  const int rbase = (lane >> 4) * 4, cbase = lane & 15;
#pragma unroll
  for (int mf = 0; mf < 4; ++mf) {
#pragma unroll
    for (int nf = 0; nf < 4; ++nf) {
      const int gcol = n0 + woffN + nf * 16 + cbase;
      float bn = (BIASMODE == 1) ? bias[gcol] : 0.f;
#pragma unroll
      for (int r = 0; r < 4; ++r) {
        const int grow = m0 + woffM + mf * 16 + rbase + r;
        const size_t idx = (size_t)zb * sC + (size_t)grow * ldc + gcol;
        float v = acc[mf][nf][r];
        if constexpr (BIASMODE == 2) v += bias[grow]; else v += bn;
        if constexpr (OUTMODE == 0) {
          ((short*)Cptr)[idx] = f2bs(v);
        } else if constexpr (OUTMODE == 1) {
          ((float*)Cptr)[idx] = v;
        } else if constexpr (OUTMODE == 2) {
          ((float*)Cptr)[idx] = 1.0f / (1.0f + __expf(-v * scale));
        } else {
          float p = 1.0f / (1.0f + __expf(-v * scale));
          ((float*)Cptr)[idx] = p;
          C2p[idx] = f2bs(p);
        }
      }
    }
  }
}

extern "C" void kernel_launch(void* const* d_in, const int* in_sizes, int n_in,
                              void* d_out, int out_size, void* d_ws, size_t ws_size,
                              hipStream_t stream) {
  const float* in1 = (const float*)d_in[0];   // [16][512][2048]
  const float* in2 = (const float*)d_in[1];   // [16][768][1024]
  const float* Wq1 = (const float*)d_in[2];  const float* bq1 = (const float*)d_in[3];
  const float* Wk1 = (const float*)d_in[4];  const float* bk1 = (const float*)d_in[5];
  const float* Wv1 = (const float*)d_in[6];  const float* bv1 = (const float*)d_in[7];
  const float* Wq2 = (const float*)d_in[8];  const float* bq2 = (const float*)d_in[9];
  const float* Wk2 = (const float*)d_in[10]; const float* bk2 = (const float*)d_in[11];
  const float* Wv2 = (const float*)d_in[12]; const float* bv2 = (const float*)d_in[13];

  float* out = (float*)d_out;
  float* ctx2   = out;                                      // [16][2048][512]
  float* probs2 = out + (size_t)16 * 2048 * 512;            // [16][2048][1024]
  float* ctx1   = probs2 + (size_t)16 * 2048 * 1024;        // [16][1024][512]
  float* probs1 = ctx1 + (size_t)16 * 1024 * 512;           // [16][1024][2048]

  char* ws = (char*)d_ws;
  constexpr size_t O_WQ1T = 0;
  constexpr size_t O_WK1T = O_WQ1T + (size_t)512 * 512 * 2;
  constexpr size_t O_WV1T = O_WK1T + (size_t)512 * 512 * 2;
  constexpr size_t O_WQ2T = O_WV1T + (size_t)512 * 512 * 2;
  constexpr size_t O_WK2T = O_WQ2T + (size_t)768 * 512 * 2;
  constexpr size_t O_WV2T = O_WK2T + (size_t)768 * 512 * 2;
  constexpr size_t O_B1   = O_WV2T + (size_t)768 * 512 * 2;
  constexpr size_t O_B2   = O_B1 + 4096;
  constexpr size_t O_QK1  = O_B2 + 4096;                          // [32768][1024]
  constexpr size_t O_V1T  = O_QK1 + (size_t)32768 * 1024 * 2;     // [16][512][2048]
  constexpr size_t O_QK2  = O_V1T + (size_t)16 * 512 * 2048 * 2;  // [16384][1024]
  constexpr size_t O_V2T  = O_QK2 + (size_t)16384 * 1024 * 2;     // [16][512][1024]
  constexpr size_t O_X1B  = O_V2T + (size_t)16 * 512 * 1024 * 2;  // [32768][512]
  constexpr size_t O_X2B  = O_X1B + (size_t)32768 * 512 * 2;      // [16384][768]
  constexpr size_t O_PB1  = O_X2B + (size_t)16384 * 768 * 2;      // bf16 probs1
  constexpr size_t O_PB2  = O_PB1 + (size_t)16 * 1024 * 2048 * 2; // bf16 probs2
  constexpr size_t NEED_A = O_PB2 + (size_t)16 * 2048 * 1024 * 2;
  constexpr size_t NEED_B = O_PB1;

  short* wq1t = (short*)(ws + O_WQ1T);
  short* wk1t = (short*)(ws + O_WK1T);
  short* wv1t = (short*)(ws + O_WV1T);
  short* wq2t = (short*)(ws + O_WQ2T);
  short* wk2t = (short*)(ws + O_WK2T);
  short* wv2t = (short*)(ws + O_WV2T);
  float* b1c  = (float*)(ws + O_B1);
  float* b2c  = (float*)(ws + O_B2);
  short* qk1  = (short*)(ws + O_QK1);
  short* v1t  = (short*)(ws + O_V1T);
  short* qk2  = (short*)(ws + O_QK2);
  short* v2t  = (short*)(ws + O_V2T);
  short* x1b  = (short*)(ws + O_X1B);
  short* x2b  = (short*)(ws + O_X2B);
  short* pb1  = (short*)(ws + O_PB1);
  short* pb2  = (short*)(ws + O_PB2);

  const bool tierA = ws_size >= NEED_A;
  const bool tierB = ws_size >= NEED_B;
  if (!tierB) { x1b = (short*)probs1; x2b = (short*)probs2; }

  dim3 blk256(256), blk512(512);
  dim3 blkT(32, 8);

  // ---- stage 0 ----
  transpose_cvt<<<dim3(64, 8, 16), blkT, 0, stream>>>(in1, x1b, 512, 2048);
  transpose_cvt<<<dim3(32, 12, 16), blkT, 0, stream>>>(in2, x2b, 768, 1024);
  prep_weights<<<dim3(16, 12, 7), blkT, 0, stream>>>(
      Wq1, Wk1, Wv1, Wq2, Wk2, Wv2, wq1t, wk1t, wv1t, wq2t, wk2t, wv2t,
      bq1, bk1, bq2, bk2, b1c, b2c);

  const float scale = 0.04419417382415922f;  // 1/sqrt(512)
  const short* q1p = qk1;        // lda 1024
  const short* k1p = qk1 + 512;
  const short* q2p = qk2;
  const short* k2p = qk2 + 512;

  if (tierA) {
    // ---- stage 1: projections ----
    gemm8<0, 1, 8><<<dim3(4, 128, 1), blk512, 0, stream>>>(
        x1b, wq1t, b1c, qk1, nullptr, 512, 512, 512, 1024, 0, 0, 0, 1.f);
    gemm8<0, 1, 8><<<dim3(4, 64, 1), blk512, 0, stream>>>(
        x2b, wq2t, b2c, qk2, nullptr, 768, 768, 768, 1024, 0, 0, 0, 1.f);
    gemm8<0, 2, 8><<<dim3(8, 2, 16), blk512, 0, stream>>>(
        wv1t, x1b, bv1, v1t, nullptr, 512, 512, 512, 2048,
        0, (long long)2048 * 512, (long long)512 * 2048, 1.f);
    gemm8<0, 2, 4><<<dim3(4, 4, 16), blk512, 0, stream>>>(
        wv2t, x2b, bv2, v2t, nullptr, 768, 768, 768, 1024,
        0, (long long)1024 * 768, (long long)512 * 1024, 1.f);
    // ---- stage 2: scores + sigmoid (dual store f32 + bf16) ----
    gemm8<3, 0, 8><<<dim3(8, 4, 16), blk512, 0, stream>>>(
        q2p, k1p, nullptr, probs1, pb1, 512, 1024, 1024, 2048,
        (long long)1024 * 1024, (long long)2048 * 1024, (long long)1024 * 2048, scale);
    gemm8<3, 0, 8><<<dim3(4, 8, 16), blk512, 0, stream>>>(
        q1p, k2p, nullptr, probs2, pb2, 512, 1024, 1024, 1024,
        (long long)2048 * 1024, (long long)1024 * 1024, (long long)2048 * 1024, scale);
    // ---- stage 3: ctx = probs(bf16) @ v^T ----
    gemm8<1, 0, 4><<<dim3(2, 8, 16), blk512, 0, stream>>>(
        pb1, v1t, nullptr, ctx1, nullptr, 2048, 2048, 2048, 512,
        (long long)1024 * 2048, (long long)512 * 2048, (long long)1024 * 512, 1.f);
    gemm8<1, 0, 8><<<dim3(2, 8, 16), blk512, 0, stream>>>(
        pb2, v2t, nullptr, ctx2, nullptr, 1024, 1024, 1024, 512,
        (long long)2048 * 1024, (long long)512 * 1024, (long long)2048 * 512, 1.f);
  } else {
    gemm_bt<0, 1, 0><<<dim3(8, 256, 1), blk256, 0, stream>>>(
        x1b, wq1t, b1c, qk1, nullptr, 512, 512, 512, 1024, 0, 0, 0, 1.f);
    gemm_bt<0, 1, 0><<<dim3(8, 128, 1), blk256, 0, stream>>>(
        x2b, wq2t, b2c, qk2, nullptr, 768, 768, 768, 1024, 0, 0, 0, 1.f);
    gemm_bt<0, 2, 0><<<dim3(16, 4, 16), blk256, 0, stream>>>(
        wv1t, x1b, bv1, v1t, nullptr, 512, 512, 512, 2048,
        0, (long long)2048 * 512, (long long)512 * 2048, 1.f);
    gemm_bt<0, 2, 0><<<dim3(8, 4, 16), blk256, 0, stream>>>(
        wv2t, x2b, bv2, v2t, nullptr, 768, 768, 768, 1024,
        0, (long long)1024 * 768, (long long)512 * 1024, 1.f);
    gemm_bt<2, 0, 0><<<dim3(16, 8, 16), blk256, 0, stream>>>(
        q2p, k1p, nullptr, probs1, nullptr, 512, 1024, 1024, 2048,
        (long long)1024 * 1024, (long long)2048 * 1024, (long long)1024 * 2048, scale);
    gemm_bt<2, 0, 0><<<dim3(8, 16, 16), blk256, 0, stream>>>(
        q1p, k2p, nullptr, probs2, nullptr, 512, 1024, 1024, 1024,
        (long long)2048 * 1024, (long long)1024 * 1024, (long long)2048 * 1024, scale);
    gemm_bt<1, 0, 1><<<dim3(4, 8, 16), blk256, 0, stream>>>(
        probs1, v1t, nullptr, ctx1, nullptr, 2048, 2048, 2048, 512,
        (long long)1024 * 2048, (long long)512 * 2048, (long long)1024 * 512, 1.f);
    gemm_bt<1, 0, 1><<<dim3(4, 16, 16), blk256, 0, stream>>>(
        probs2, v2t, nullptr, ctx2, nullptr, 1024, 1024, 1024, 512,
        (long long)2048 * 1024, (long long)512 * 1024, (long long)2048 * 512, 1.f);
  }
}

// Round 6
// 458.746 us; speedup vs baseline: 1.3149x; 1.0219x over previous
//
#include <hip/hip_runtime.h>
#include <hip/hip_bf16.h>

#define DEVFN __device__ __forceinline__

typedef __attribute__((ext_vector_type(4))) float f32x4;
typedef __attribute__((ext_vector_type(8))) short s16x8;
typedef __attribute__((ext_vector_type(2))) short s16x2;
typedef __attribute__((ext_vector_type(8))) __bf16 bf16x8;

union FragU { s16x8 s; bf16x8 b; };

DEVFN short f2bs(float x) {
  union { __hip_bfloat16 h; short s; } u;
  u.h = __float2bfloat16(x);
  return u.s;
}

DEVFN void gload16(const void* g, void* l) {
  __builtin_amdgcn_global_load_lds(
      (const __attribute__((address_space(1))) void*)g,
      (__attribute__((address_space(3))) void*)l, 16, 0, 0);
}

template <int N> DEVFN void waitcnt_vm() {
  if constexpr (N == 0) asm volatile("s_waitcnt vmcnt(0)" ::: "memory");
  else if constexpr (N == 3) asm volatile("s_waitcnt vmcnt(3)" ::: "memory");
  else if constexpr (N == 4) asm volatile("s_waitcnt vmcnt(4)" ::: "memory");
  else if constexpr (N == 6) asm volatile("s_waitcnt vmcnt(6)" ::: "memory");
  else if constexpr (N == 8) asm volatile("s_waitcnt vmcnt(8)" ::: "memory");
  else static_assert(N == 0, "unsupported vmcnt");
}

// in: [Z][C][L] f32 -> out: [Z][L][C] bf16. Block (32,8): C-tile 64, L-tile 32.
__global__ __launch_bounds__(256) void transpose_cvt(
    const float* __restrict__ in, short* __restrict__ out, int C, int L) {
  __shared__ float tile[64][33];
  const int l0 = blockIdx.x * 32, c0 = blockIdx.y * 64;
  const size_t base = (size_t)blockIdx.z * C * L;
  const int tx = threadIdx.x, ty = threadIdx.y;
#pragma unroll
  for (int i = ty; i < 64; i += 8)
    tile[i][tx] = in[base + (size_t)(c0 + i) * L + l0 + tx];
  __syncthreads();
#pragma unroll
  for (int i = ty; i < 32; i += 8) {
    s16x2 v;
    v[0] = f2bs(tile[2 * tx][i]);
    v[1] = f2bs(tile[2 * tx + 1][i]);
    *(s16x2*)&out[base + (size_t)(l0 + i) * C + c0 + 2 * tx] = v;
  }
}

// All six weight transposes + both bias concats, one launch.
__global__ __launch_bounds__(256) void prep_weights(
    const float* __restrict__ Wq1, const float* __restrict__ Wk1,
    const float* __restrict__ Wv1, const float* __restrict__ Wq2,
    const float* __restrict__ Wk2, const float* __restrict__ Wv2,
    short* wq1t, short* wk1t, short* wv1t,
    short* wq2t, short* wk2t, short* wv2t,
    const float* __restrict__ bq1, const float* __restrict__ bk1,
    const float* __restrict__ bq2, const float* __restrict__ bk2,
    float* b1c, float* b2c) {
  const int z = blockIdx.z;
  if (z == 6) {
    if (blockIdx.y != 0 || blockIdx.x >= 8) return;
    const int bx = blockIdx.x;
    const int tid = threadIdx.y * 32 + threadIdx.x;
    const int i = (bx & 3) * 256 + tid;
    const float* s = (bx < 4) ? ((i < 512) ? bq1 : bk1)
                              : ((i < 512) ? bq2 : bk2);
    float* d = (bx < 4) ? b1c : b2c;
    d[i] = s[i & 511];
    return;
  }
  const float* W; short* O; int C;
  switch (z) {
    case 0: W = Wq1; O = wq1t; C = 512; break;
    case 1: W = Wk1; O = wk1t; C = 512; break;
    case 2: W = Wv1; O = wv1t; C = 512; break;
    case 3: W = Wq2; O = wq2t; C = 768; break;
    case 4: W = Wk2; O = wk2t; C = 768; break;
    default: W = Wv2; O = wv2t; C = 768; break;
  }
  if (blockIdx.y * 64 >= (unsigned)C) return;
  const int L = 512;
  __shared__ float tile[64][33];
  const int l0 = blockIdx.x * 32, c0 = blockIdx.y * 64;
  const int tx = threadIdx.x, ty = threadIdx.y;
#pragma unroll
  for (int i = ty; i < 64; i += 8)
    tile[i][tx] = W[(size_t)(c0 + i) * L + l0 + tx];
  __syncthreads();
#pragma unroll
  for (int i = ty; i < 32; i += 8) {
    s16x2 v;
    v[0] = f2bs(tile[2 * tx][i]);
    v[1] = f2bs(tile[2 * tx + 1][i]);
    *(s16x2*)&O[(size_t)(l0 + i) * C + c0 + 2 * tx] = v;
  }
}

// ---------------------------------------------------------------------------
// Deep-pipelined, phase-split GEMM with XCD-aware block remap.
// C[m][n] = sum_k A[m][k]*Bt[n][k] (+bias). Tile BM x 256, BM = MR*32.
// 8 waves (2M x 4N); per-wave (MR*16) x 64 = acc[MR][4]. BK=32.
// 4 LDS buffers, prefetch depth 3; steady-state vmcnt(2*LPT); tail cascade.
// XCD remap (T1): hw linear id h -> logical l = (h%8)*(NB/8) + h/8 when
// NB%8==0 (bijective); groups each batch's blocks on one XCD so operand
// panels stay L2-resident (per-batch working set ~3MB < 4MiB XCD L2).
// OUTMODE: 0=bf16, 1=f32, 2=sigmoid f32, 3=sigmoid f32 + bf16 to C2p
// BIASMODE: 0 none, 1 per-n, 2 per-m.
// ---------------------------------------------------------------------------
template <int OUTMODE, int BIASMODE, int MR>
__global__ __launch_bounds__(512, 2) void gemm8(
    const short* __restrict__ Ap, const short* __restrict__ Btp,
    const float* __restrict__ bias, void* __restrict__ Cptr,
    short* __restrict__ C2p,
    int K, int lda, int ldb, int ldc,
    long long sA, long long sB, long long sC, float scale) {
  constexpr int BM = MR * 32;
  constexpr int BN = 256;
  constexpr int LA = BM / 128;        // gloads/thread for A tile
  constexpr int LB = BN / 128;        // gloads/thread for B tile
  constexpr int LPT = LA + LB;
  constexpr int ABYTES = BM * 64;     // BM x 32k x 2B
  constexpr int BUFB = (BM + BN) * 64;
  constexpr int MH = MR / 2;
  __shared__ __align__(16) char smem[4 * BUFB];
  const int tid = threadIdx.x;
  const int lane = tid & 63, wid = tid >> 6;
  const int wm = wid >> 2, wn = wid & 3;

  // ---- XCD-aware bijective block remap (T1) ----
  const unsigned gx = gridDim.x, gy = gridDim.y, gz = gridDim.z;
  const unsigned NB = gx * gy * gz;
  unsigned h = blockIdx.x + gx * (blockIdx.y + gy * blockIdx.z);
  unsigned l = ((NB & 7u) == 0u) ? (h & 7u) * (NB >> 3) + (h >> 3) : h;
  const unsigned bx = l % gx;
  const unsigned rem = l / gx;
  const unsigned by = rem % gy;
  const unsigned bz = rem / gy;

  const int zb = bz;
  const int m0 = by * BM, n0 = bx * BN;
  const char* Ab = (const char*)(Ap + (size_t)zb * sA);
  const char* Bb = (const char*)(Btp + (size_t)zb * sB);
  const size_t lda2 = (size_t)lda * 2, ldb2 = (size_t)ldb * 2;

  // Staging: dest d = j*8192 + tid*16 (linear). Inverse-map to (row, colbyte).
  int s_r[2], s_cb[2];
#pragma unroll
  for (int j = 0; j < 2; ++j) {
    const int d = j * 8192 + tid * 16;
    const int line = d >> 7;
    s_r[j] = line * 2 + ((d >> 6) & 1);
    s_cb[j] = (d & 63) ^ ((line & 3) << 4);
  }

  f32x4 acc[MR][4] = {};
  const int frow = lane & 15, fkg = lane >> 4;

  int ra[MR], rb[4];
#pragma unroll
  for (int mf = 0; mf < MR; ++mf) {
    const int R = wm * (MR * 16) + mf * 16 + frow;
    ra[mf] = (R >> 1) * 128 + (R & 1) * 64 + ((fkg * 16) ^ (((R >> 1) & 3) << 4));
  }
#pragma unroll
  for (int nf = 0; nf < 4; ++nf) {
    const int R = wn * 64 + nf * 16 + frow;
    rb[nf] = (R >> 1) * 128 + (R & 1) * 64 + ((fkg * 16) ^ (((R >> 1) & 3) << 4));
  }

  const int NT = K >> 5;

#define STAGE_A(t)                                                       \
  {                                                                      \
    char* base_ = smem + ((t) & 3) * BUFB;                               \
    const size_t kb_ = (size_t)(t) * 64;                                 \
    _Pragma("unroll")                                                    \
    for (int j = 0; j < LA; ++j)                                         \
      gload16(Ab + (size_t)(m0 + s_r[j]) * lda2 + kb_ + s_cb[j],         \
              base_ + j * 8192 + tid * 16);                              \
  }
#define STAGE_B(t)                                                       \
  {                                                                      \
    char* base_ = smem + ((t) & 3) * BUFB + ABYTES;                      \
    const size_t kb_ = (size_t)(t) * 64;                                 \
    _Pragma("unroll")                                                    \
    for (int j = 0; j < LB; ++j)                                         \
      gload16(Bb + (size_t)(n0 + s_r[j]) * ldb2 + kb_ + s_cb[j],         \
              base_ + j * 8192 + tid * 16);                              \
  }

  // prologue: 3 tiles in flight, wait for tile 0 (NT >= 3 at all call sites)
  STAGE_A(0); STAGE_B(0);
  STAGE_A(1); STAGE_B(1);
  STAGE_A(2); STAGE_B(2);
  waitcnt_vm<2 * LPT>();
  __builtin_amdgcn_sched_barrier(0);
  __builtin_amdgcn_s_barrier();
  __builtin_amdgcn_sched_barrier(0);

  for (int t = 0; t < NT; ++t) {
    const char* la = smem + (t & 3) * BUFB;
    const char* lb = la + ABYTES;
    FragU fa[MR], fb[4];
    // ---- phase 1: stage A(t+3) | read fa[0..MH), fb[0..4) | MFMA mf<MH ----
    if (t + 3 < NT) STAGE_A(t + 3);
#pragma unroll
    for (int mf = 0; mf < MH; ++mf) fa[mf].s = *(const s16x8*)(la + ra[mf]);
#pragma unroll
    for (int nf = 0; nf < 4; ++nf) fb[nf].s = *(const s16x8*)(lb + rb[nf]);
    __builtin_amdgcn_s_barrier();
    asm volatile("s_waitcnt lgkmcnt(0)" ::: "memory");
    __builtin_amdgcn_sched_barrier(0);
    __builtin_amdgcn_s_setprio(1);
#pragma unroll
    for (int mf = 0; mf < MH; ++mf)
#pragma unroll
      for (int nf = 0; nf < 4; ++nf)
        acc[mf][nf] = __builtin_amdgcn_mfma_f32_16x16x32_bf16(
            fa[mf].b, fb[nf].b, acc[mf][nf], 0, 0, 0);
    __builtin_amdgcn_s_setprio(0);
    __builtin_amdgcn_s_barrier();
    // ---- phase 2: stage B(t+3) | read fa[MH..MR) | MFMA mf>=MH ----
    if (t + 3 < NT) STAGE_B(t + 3);
#pragma unroll
    for (int mf = MH; mf < MR; ++mf) fa[mf].s = *(const s16x8*)(la + ra[mf]);
    __builtin_amdgcn_s_barrier();
    asm volatile("s_waitcnt lgkmcnt(0)" ::: "memory");
    __builtin_amdgcn_sched_barrier(0);
    __builtin_amdgcn_s_setprio(1);
#pragma unroll
    for (int mf = MH; mf < MR; ++mf)
#pragma unroll
      for (int nf = 0; nf < 4; ++nf)
        acc[mf][nf] = __builtin_amdgcn_mfma_f32_16x16x32_bf16(
            fa[mf].b, fb[nf].b, acc[mf][nf], 0, 0, 0);
    __builtin_amdgcn_s_setprio(0);
    // ---- end-of-iter wait (same verified schedule) ----
    if (t + 3 < NT) {
      waitcnt_vm<2 * LPT>();
    } else if (t + 2 < NT) {
      waitcnt_vm<LPT>();
    } else if (t + 1 < NT) {
      waitcnt_vm<0>();
    } else {
      break;  // last iteration: no further LDS reads
    }
    __builtin_amdgcn_sched_barrier(0);
    __builtin_amdgcn_s_barrier();
    __builtin_amdgcn_sched_barrier(0);
  }
#undef STAGE_A
#undef STAGE_B

  const int rbase = (lane >> 4) * 4, cbase = lane & 15;
#pragma unroll
  for (int mf = 0; mf < MR; ++mf) {
#pragma unroll
    for (int nf = 0; nf < 4; ++nf) {
      const int gcol = n0 + wn * 64 + nf * 16 + cbase;
      float bn = (BIASMODE == 1) ? bias[gcol] : 0.f;
#pragma unroll
      for (int r = 0; r < 4; ++r) {
        const int grow = m0 + wm * (MR * 16) + mf * 16 + rbase + r;
        const size_t idx = (size_t)zb * sC + (size_t)grow * ldc + gcol;
        float v = acc[mf][nf][r];
        if constexpr (BIASMODE == 2) v += bias[grow]; else v += bn;
        if constexpr (OUTMODE == 0) {
          ((short*)Cptr)[idx] = f2bs(v);
        } else if constexpr (OUTMODE == 1) {
          ((float*)Cptr)[idx] = v;
        } else if constexpr (OUTMODE == 2) {
          ((float*)Cptr)[idx] = 1.0f / (1.0f + __expf(-v * scale));
        } else {
          float p = 1.0f / (1.0f + __expf(-v * scale));
          ((float*)Cptr)[idx] = p;
          C2p[idx] = f2bs(p);
        }
      }
    }
  }
}

// ---------------------------------------------------------------------------
// Fallback (tierB only): gload-staged 128x128 BK=64 GEMM, AF32 supported.
// ---------------------------------------------------------------------------
template <int OUTMODE, int BIASMODE, int AF32>
__global__ __launch_bounds__(256) void gemm_bt(
    const void* __restrict__ Aptr, const short* __restrict__ Btp,
    const float* __restrict__ bias, void* __restrict__ Cptr,
    short* __restrict__ C2p,
    int K, int lda, int ldb, int ldc,
    long long sA, long long sB, long long sC, float scale) {
  __shared__ __align__(16) short lsA[128 * 64];
  __shared__ __align__(16) short lsB[128 * 64];
  const int tid = threadIdx.x;
  const int lane = tid & 63, wid = tid >> 6;
  const int zb = blockIdx.z;
  const int m0 = blockIdx.y * 128, n0 = blockIdx.x * 128;
  const short* Ab = AF32 ? nullptr : (const short*)Aptr + (size_t)zb * sA;
  const float* Af = AF32 ? (const float*)Aptr + (size_t)zb * sA : nullptr;
  const short* Bt = Btp + (size_t)zb * sB;

  f32x4 acc[4][4] = {};
  const int woffM = (wid >> 1) * 64, woffN = (wid & 1) * 64;
  const int frow = lane & 15, fkg = lane >> 4;

  for (int k0 = 0; k0 < K; k0 += 64) {
    if (k0) __syncthreads();
    if constexpr (!AF32) {
#pragma unroll
      for (int i = 0; i < 4; ++i) {
        const int f = i * 4096 + tid * 16;
        const int row = f >> 7, colb = f & 127;
        gload16((const char*)Ab + ((size_t)(m0 + row) * lda + k0) * 2 + colb,
                (char*)lsA + f);
      }
    } else {
#pragma unroll
      for (int i = 0; i < 8; ++i) {
        int f = tid + i * 256;
        int row = f >> 4, c4 = f & 15;
        f32x4 v = *(const f32x4*)&Af[(size_t)(m0 + row) * lda + k0 + c4 * 4];
        union { short s[4]; unsigned long long q; } cv;
#pragma unroll
        for (int j = 0; j < 4; ++j) cv.s[j] = f2bs(v[j]);
        *(unsigned long long*)&lsA[row * 64 + c4 * 4] = cv.q;
      }
    }
#pragma unroll
    for (int i = 0; i < 4; ++i) {
      const int f = i * 4096 + tid * 16;
      const int row = f >> 7, colb = f & 127;
      gload16((const char*)Bt + ((size_t)(n0 + row) * ldb + k0) * 2 + colb,
              (char*)lsB + f);
    }
    __syncthreads();
#pragma unroll
    for (int kk = 0; kk < 2; ++kk) {
      const int kb = kk * 32 + fkg * 8;
      FragU fa[4], fb[4];
#pragma unroll
      for (int mf = 0; mf < 4; ++mf)
        fa[mf].s = *(const s16x8*)&lsA[(woffM + mf * 16 + frow) * 64 + kb];
#pragma unroll
      for (int nf = 0; nf < 4; ++nf)
        fb[nf].s = *(const s16x8*)&lsB[(woffN + nf * 16 + frow) * 64 + kb];
#pragma unroll
      for (int mf = 0; mf < 4; ++mf)
#pragma unroll
        for (int nf = 0; nf < 4; ++nf)
          acc[mf][nf] = __builtin_amdgcn_mfma_f32_16x16x32_bf16(
              fa[mf].b, fb[nf].b, acc[mf][nf], 0, 0, 0);
    }
  }

  const int rbase = (lane >> 4) * 4, cbase = lane & 15;
#pragma unroll
  for (int mf = 0; mf < 4; ++mf) {
#pragma unroll
    for (int nf = 0; nf < 4; ++nf) {
      const int gcol = n0 + woffN + nf * 16 + cbase;
      float bn = (BIASMODE == 1) ? bias[gcol] : 0.f;
#pragma unroll
      for (int r = 0; r < 4; ++r) {
        const int grow = m0 + woffM + mf * 16 + rbase + r;
        const size_t idx = (size_t)zb * sC + (size_t)grow * ldc + gcol;
        float v = acc[mf][nf][r];
        if constexpr (BIASMODE == 2) v += bias[grow]; else v += bn;
        if constexpr (OUTMODE == 0) {
          ((short*)Cptr)[idx] = f2bs(v);
        } else if constexpr (OUTMODE == 1) {
          ((float*)Cptr)[idx] = v;
        } else if constexpr (OUTMODE == 2) {
          ((float*)Cptr)[idx] = 1.0f / (1.0f + __expf(-v * scale));
        } else {
          float p = 1.0f / (1.0f + __expf(-v * scale));
          ((float*)Cptr)[idx] = p;
          C2p[idx] = f2bs(p);
        }
      }
    }
  }
}

extern "C" void kernel_launch(void* const* d_in, const int* in_sizes, int n_in,
                              void* d_out, int out_size, void* d_ws, size_t ws_size,
                              hipStream_t stream) {
  const float* in1 = (const float*)d_in[0];   // [16][512][2048]
  const float* in2 = (const float*)d_in[1];   // [16][768][1024]
  const float* Wq1 = (const float*)d_in[2];  const float* bq1 = (const float*)d_in[3];
  const float* Wk1 = (const float*)d_in[4];  const float* bk1 = (const float*)d_in[5];
  const float* Wv1 = (const float*)d_in[6];  const float* bv1 = (const float*)d_in[7];
  const float* Wq2 = (const float*)d_in[8];  const float* bq2 = (const float*)d_in[9];
  const float* Wk2 = (const float*)d_in[10]; const float* bk2 = (const float*)d_in[11];
  const float* Wv2 = (const float*)d_in[12]; const float* bv2 = (const float*)d_in[13];

  float* out = (float*)d_out;
  float* ctx2   = out;                                      // [16][2048][512]
  float* probs2 = out + (size_t)16 * 2048 * 512;            // [16][2048][1024]
  float* ctx1   = probs2 + (size_t)16 * 2048 * 1024;        // [16][1024][512]
  float* probs1 = ctx1 + (size_t)16 * 1024 * 512;           // [16][1024][2048]

  char* ws = (char*)d_ws;
  constexpr size_t O_WQ1T = 0;
  constexpr size_t O_WK1T = O_WQ1T + (size_t)512 * 512 * 2;
  constexpr size_t O_WV1T = O_WK1T + (size_t)512 * 512 * 2;
  constexpr size_t O_WQ2T = O_WV1T + (size_t)512 * 512 * 2;
  constexpr size_t O_WK2T = O_WQ2T + (size_t)768 * 512 * 2;
  constexpr size_t O_WV2T = O_WK2T + (size_t)768 * 512 * 2;
  constexpr size_t O_B1   = O_WV2T + (size_t)768 * 512 * 2;
  constexpr size_t O_B2   = O_B1 + 4096;
  constexpr size_t O_QK1  = O_B2 + 4096;                          // [32768][1024]
  constexpr size_t O_V1T  = O_QK1 + (size_t)32768 * 1024 * 2;     // [16][512][2048]
  constexpr size_t O_QK2  = O_V1T + (size_t)16 * 512 * 2048 * 2;  // [16384][1024]
  constexpr size_t O_V2T  = O_QK2 + (size_t)16384 * 1024 * 2;     // [16][512][1024]
  constexpr size_t O_X1B  = O_V2T + (size_t)16 * 512 * 1024 * 2;  // [32768][512]
  constexpr size_t O_X2B  = O_X1B + (size_t)32768 * 512 * 2;      // [16384][768]
  constexpr size_t O_PB1  = O_X2B + (size_t)16384 * 768 * 2;      // bf16 probs1
  constexpr size_t O_PB2  = O_PB1 + (size_t)16 * 1024 * 2048 * 2; // bf16 probs2
  constexpr size_t NEED_A = O_PB2 + (size_t)16 * 2048 * 1024 * 2;
  constexpr size_t NEED_B = O_PB1;

  short* wq1t = (short*)(ws + O_WQ1T);
  short* wk1t = (short*)(ws + O_WK1T);
  short* wv1t = (short*)(ws + O_WV1T);
  short* wq2t = (short*)(ws + O_WQ2T);
  short* wk2t = (short*)(ws + O_WK2T);
  short* wv2t = (short*)(ws + O_WV2T);
  float* b1c  = (float*)(ws + O_B1);
  float* b2c  = (float*)(ws + O_B2);
  short* qk1  = (short*)(ws + O_QK1);
  short* v1t  = (short*)(ws + O_V1T);
  short* qk2  = (short*)(ws + O_QK2);
  short* v2t  = (short*)(ws + O_V2T);
  short* x1b  = (short*)(ws + O_X1B);
  short* x2b  = (short*)(ws + O_X2B);
  short* pb1  = (short*)(ws + O_PB1);
  short* pb2  = (short*)(ws + O_PB2);

  const bool tierA = ws_size >= NEED_A;
  const bool tierB = ws_size >= NEED_B;
  if (!tierB) { x1b = (short*)probs1; x2b = (short*)probs2; }

  dim3 blk256(256), blk512(512);
  dim3 blkT(32, 8);

  // ---- stage 0 ----
  transpose_cvt<<<dim3(64, 8, 16), blkT, 0, stream>>>(in1, x1b, 512, 2048);
  transpose_cvt<<<dim3(32, 12, 16), blkT, 0, stream>>>(in2, x2b, 768, 1024);
  prep_weights<<<dim3(16, 12, 7), blkT, 0, stream>>>(
      Wq1, Wk1, Wv1, Wq2, Wk2, Wv2, wq1t, wk1t, wv1t, wq2t, wk2t, wv2t,
      bq1, bk1, bq2, bk2, b1c, b2c);

  const float scale = 0.04419417382415922f;  // 1/sqrt(512)
  const short* q1p = qk1;        // lda 1024
  const short* k1p = qk1 + 512;
  const short* q2p = qk2;
  const short* k2p = qk2 + 512;

  if (tierA) {
    // ---- stage 1: projections ----
    gemm8<0, 1, 8><<<dim3(4, 128, 1), blk512, 0, stream>>>(
        x1b, wq1t, b1c, qk1, nullptr, 512, 512, 512, 1024, 0, 0, 0, 1.f);
    gemm8<0, 1, 8><<<dim3(4, 64, 1), blk512, 0, stream>>>(
        x2b, wq2t, b2c, qk2, nullptr, 768, 768, 768, 1024, 0, 0, 0, 1.f);
    gemm8<0, 2, 8><<<dim3(8, 2, 16), blk512, 0, stream>>>(
        wv1t, x1b, bv1, v1t, nullptr, 512, 512, 512, 2048,
        0, (long long)2048 * 512, (long long)512 * 2048, 1.f);
    gemm8<0, 2, 4><<<dim3(4, 4, 16), blk512, 0, stream>>>(
        wv2t, x2b, bv2, v2t, nullptr, 768, 768, 768, 1024,
        0, (long long)1024 * 768, (long long)512 * 1024, 1.f);
    // ---- stage 2: scores + sigmoid (dual store f32 + bf16) ----
    gemm8<3, 0, 8><<<dim3(8, 4, 16), blk512, 0, stream>>>(
        q2p, k1p, nullptr, probs1, pb1, 512, 1024, 1024, 2048,
        (long long)1024 * 1024, (long long)2048 * 1024, (long long)1024 * 2048, scale);
    gemm8<3, 0, 8><<<dim3(4, 8, 16), blk512, 0, stream>>>(
        q1p, k2p, nullptr, probs2, pb2, 512, 1024, 1024, 1024,
        (long long)2048 * 1024, (long long)1024 * 1024, (long long)2048 * 1024, scale);
    // ---- stage 3: ctx = probs(bf16) @ v^T ----
    gemm8<1, 0, 4><<<dim3(2, 8, 16), blk512, 0, stream>>>(
        pb1, v1t, nullptr, ctx1, nullptr, 2048, 2048, 2048, 512,
        (long long)1024 * 2048, (long long)512 * 2048, (long long)1024 * 512, 1.f);
    gemm8<1, 0, 8><<<dim3(2, 8, 16), blk512, 0, stream>>>(
        pb2, v2t, nullptr, ctx2, nullptr, 1024, 1024, 1024, 512,
        (long long)2048 * 1024, (long long)512 * 1024, (long long)2048 * 512, 1.f);
  } else {
    gemm_bt<0, 1, 0><<<dim3(8, 256, 1), blk256, 0, stream>>>(
        x1b, wq1t, b1c, qk1, nullptr, 512, 512, 512, 1024, 0, 0, 0, 1.f);
    gemm_bt<0, 1, 0><<<dim3(8, 128, 1), blk256, 0, stream>>>(
        x2b, wq2t, b2c, qk2, nullptr, 768, 768, 768, 1024, 0, 0, 0, 1.f);
    gemm_bt<0, 2, 0><<<dim3(16, 4, 16), blk256, 0, stream>>>(
        wv1t, x1b, bv1, v1t, nullptr, 512, 512, 512, 2048,
        0, (long long)2048 * 512, (long long)512 * 2048, 1.f);
    gemm_bt<0, 2, 0><<<dim3(8, 4, 16), blk256, 0, stream>>>(
        wv2t, x2b, bv2, v2t, nullptr, 768, 768, 768, 1024,
        0, (long long)1024 * 768, (long long)512 * 1024, 1.f);
    gemm_bt<2, 0, 0><<<dim3(16, 8, 16), blk256, 0, stream>>>(
        q2p, k1p, nullptr, probs1, nullptr, 512, 1024, 1024, 2048,
        (long long)1024 * 1024, (long long)2048 * 1024, (long long)1024 * 2048, scale);
    gemm_bt<2, 0, 0><<<dim3(8, 16, 16), blk256, 0, stream>>>(
        q1p, k2p, nullptr, probs2, nullptr, 512, 1024, 1024, 1024,
        (long long)2048 * 1024, (long long)1024 * 1024, (long long)2048 * 1024, scale);
    gemm_bt<1, 0, 1><<<dim3(4, 8, 16), blk256, 0, stream>>>(
        probs1, v1t, nullptr, ctx1, nullptr, 2048, 2048, 2048, 512,
        (long long)1024 * 2048, (long long)512 * 2048, (long long)1024 * 512, 1.f);
    gemm_bt<1, 0, 1><<<dim3(4, 16, 16), blk256, 0, stream>>>(
        probs2, v2t, nullptr, ctx2, nullptr, 1024, 1024, 1024, 512,
        (long long)2048 * 1024, (long long)512 * 1024, (long long)2048 * 512, 1.f);
  }
}